// Round 2
// baseline (3275.220 us; speedup 1.0000x reference)
//
#include <hip/hip_runtime.h>
#include <hip/hip_bf16.h>
#include <cstddef>
#include <cstdint>

#define D_MODEL     1024
#define D_INNER     2048
#define D_STATE     128
#define NHEADS      16
#define HEADDIM     128
#define D_CONV      4
#define CHUNK       256
#define CONV_DIM    2304      // D_INNER + 2*D_STATE
#define DIM_IN_PROJ 4368      // 2*D_INNER + 2*D_STATE + NHEADS
#define BATCH       2
#define SEQ         4096
#define ROWS        8192      // BATCH*SEQ
#define NC          16        // SEQ/CHUNK
#define EPS         1e-5f

typedef __hip_bfloat16 bf16;

__device__ __forceinline__ float sigmoidf_(float x) { return 1.f / (1.f + expf(-x)); }

__device__ __forceinline__ float ldf(const float* p) { return *p; }
__device__ __forceinline__ float ldf(const bf16* p)  { return __bfloat162float(*p); }
__device__ __forceinline__ void  stf(float* p, float v) { *p = v; }
__device__ __forceinline__ void  stf(bf16* p, float v)  { *p = __float2bfloat16(v); }

// ---------------------------------------------------------------------------
// Generic batched GEMM:  C[M][N] = A[M][K] * B[N][K]^T   (row-major, fp32 acc)
// ---------------------------------------------------------------------------
template<typename TA, typename TB, typename TC, int BM, int BN, int BK, int TM, int TN>
__global__ __launch_bounds__(256) void gemm_abt(
    const TA* __restrict__ A, const TB* __restrict__ B, TC* __restrict__ C,
    int M, int N, int K, int lda, int ldb, int ldc,
    long long sA, long long sB, long long sC)
{
    A += (long long)blockIdx.z * sA;
    B += (long long)blockIdx.z * sB;
    C += (long long)blockIdx.z * sC;

    __shared__ float As[BK][BM + 1];
    __shared__ float Bs[BK][BN + 1];

    const int tid  = threadIdx.x;
    const int row0 = blockIdx.y * BM;
    const int col0 = blockIdx.x * BN;
    const int tx   = tid % (BN / TN);
    const int ty   = tid / (BN / TN);

    float acc[TM][TN];
#pragma unroll
    for (int i = 0; i < TM; i++)
#pragma unroll
        for (int j = 0; j < TN; j++) acc[i][j] = 0.f;

    for (int k0 = 0; k0 < K; k0 += BK) {
        for (int i = tid; i < BM * BK; i += 256) {
            int m = i / BK, k = i % BK;
            int gm = row0 + m;
            As[k][m] = (gm < M) ? ldf(&A[(size_t)gm * lda + k0 + k]) : 0.f;
        }
        for (int i = tid; i < BN * BK; i += 256) {
            int n = i / BK, k = i % BK;
            int gn = col0 + n;
            Bs[k][n] = (gn < N) ? ldf(&B[(size_t)gn * ldb + k0 + k]) : 0.f;
        }
        __syncthreads();
#pragma unroll
        for (int k = 0; k < BK; k++) {
            float a[TM], bb[TN];
#pragma unroll
            for (int i = 0; i < TM; i++) a[i] = As[k][ty * TM + i];
#pragma unroll
            for (int j = 0; j < TN; j++) bb[j] = Bs[k][tx * TN + j];
#pragma unroll
            for (int i = 0; i < TM; i++)
#pragma unroll
                for (int j = 0; j < TN; j++) acc[i][j] += a[i] * bb[j];
        }
        __syncthreads();
    }
#pragma unroll
    for (int i = 0; i < TM; i++) {
        int gm = row0 + ty * TM + i;
        if (gm >= M) continue;
#pragma unroll
        for (int j = 0; j < TN; j++) {
            int gn = col0 + tx * TN + j;
            if (gn < N) stf(&C[(size_t)gm * ldc + gn], acc[i][j]);
        }
    }
}

// ---------------------------------------------------------------------------
// Depthwise causal conv (width 4) + bias + SiLU on the xBC slice of zxbcdt
// ---------------------------------------------------------------------------
__global__ __launch_bounds__(256) void conv_silu_kernel(
    const bf16* __restrict__ zx, const float* __restrict__ cw,
    const float* __restrict__ cb, bf16* __restrict__ xbc)
{
    int idx = blockIdx.x * 256 + threadIdx.x;
    if (idx >= ROWS * CONV_DIM) return;
    int c   = idx % CONV_DIM;
    int row = idx / CONV_DIM;
    int l   = row & (SEQ - 1);
    float acc = cb[c];
#pragma unroll
    for (int k = 0; k < D_CONV; k++) {
        int ls = l - (D_CONV - 1) + k;
        if (ls >= 0)
            acc += cw[c * D_CONV + k] *
                   __bfloat162float(zx[(size_t)(row - (D_CONV - 1) + k) * DIM_IN_PROJ + D_INNER + c]);
    }
    stf(&xbc[(size_t)row * CONV_DIM + c], acc * sigmoidf_(acc));
}

// ---------------------------------------------------------------------------
// dt = softplus(dt_raw + dt_bias)    (dt_raw kept fp32 via dedicated proj)
// ---------------------------------------------------------------------------
__global__ __launch_bounds__(256) void dt_softplus_kernel(
    const float* __restrict__ dtraw, const float* __restrict__ dt_bias,
    float* __restrict__ dtsp)
{
    int idx = blockIdx.x * 256 + threadIdx.x;   // ROWS*NHEADS
    if (idx >= ROWS * NHEADS) return;
    int h = idx % NHEADS;
    float x = dtraw[idx] + dt_bias[h];
    dtsp[idx] = (x > 20.f) ? x : log1pf(expf(x));
}

// ---------------------------------------------------------------------------
// Per-(b,c,h) inclusive cumsum of dA = dt * A over the 256-length chunk
// ---------------------------------------------------------------------------
__global__ __launch_bounds__(256) void cumsum_kernel(
    const float* __restrict__ dtsp, const float* __restrict__ A_log,
    float* __restrict__ Acs)
{
    int blk = blockIdx.x;         // (b*NC+c)*NHEADS + h
    int h   = blk % NHEADS;
    int bc  = blk / NHEADS;
    int t   = threadIdx.x;
    int row = bc * CHUNK + t;
    float A = -expf(A_log[h]);
    __shared__ float buf[CHUNK];
    buf[t] = dtsp[(size_t)row * NHEADS + h] * A;
    __syncthreads();
    for (int off = 1; off < CHUNK; off <<= 1) {
        float v = (t >= off) ? buf[t - off] : 0.f;
        __syncthreads();
        buf[t] += v;
        __syncthreads();
    }
    Acs[(size_t)blk * CHUNK + t] = buf[t];
}

// ---------------------------------------------------------------------------
// Chunk states: states[h][p][n] = sum_q  g[q] * x[q,p] * B[q,n]
// ---------------------------------------------------------------------------
__global__ __launch_bounds__(256) void states_kernel(
    const bf16* __restrict__ xbc, const float* __restrict__ dtsp,
    const float* __restrict__ Acs, float* __restrict__ states)
{
    int blk  = blockIdx.x;  // bch
    int h    = blk % NHEADS;
    int bc   = blk / NHEADS;
    int row0 = bc * CHUNK;
    int tid  = threadIdx.x;

    __shared__ float g[CHUNK];
    __shared__ float Xs[16][HEADDIM];
    __shared__ float Bs[16][D_STATE];

    {
        float last = Acs[(size_t)blk * CHUNK + CHUNK - 1];
        float a    = Acs[(size_t)blk * CHUNK + tid];
        g[tid] = dtsp[(size_t)(row0 + tid) * NHEADS + h] * expf(last - a);
    }
    __syncthreads();

    int tn = tid % 16, tp = tid / 16;
    float acc[8][8];
#pragma unroll
    for (int i = 0; i < 8; i++)
#pragma unroll
        for (int j = 0; j < 8; j++) acc[i][j] = 0.f;

    for (int q0 = 0; q0 < CHUNK; q0 += 16) {
        for (int i = tid; i < 16 * 128; i += 256) {
            int k = i / 128, p = i % 128;
            int row = row0 + q0 + k;
            Xs[k][p] = __bfloat162float(xbc[(size_t)row * CONV_DIM + h * HEADDIM + p]) * g[q0 + k];
            Bs[k][p] = __bfloat162float(xbc[(size_t)row * CONV_DIM + D_INNER + p]);
        }
        __syncthreads();
#pragma unroll
        for (int k = 0; k < 16; k++) {
            float a[8], b[8];
#pragma unroll
            for (int i = 0; i < 8; i++) a[i] = Xs[k][tp * 8 + i];
#pragma unroll
            for (int j = 0; j < 8; j++) b[j] = Bs[k][tn * 8 + j];
#pragma unroll
            for (int i = 0; i < 8; i++)
#pragma unroll
                for (int j = 0; j < 8; j++) acc[i][j] += a[i] * b[j];
        }
        __syncthreads();
    }
#pragma unroll
    for (int i = 0; i < 8; i++)
#pragma unroll
        for (int j = 0; j < 8; j++)
            states[(size_t)blk * HEADDIM * D_STATE + (size_t)(tp * 8 + i) * D_STATE + tn * 8 + j]
                = acc[i][j];
}

// ---------------------------------------------------------------------------
// Sequential inter-chunk scan, IN PLACE on states: new value = prev (carry-in)
// ---------------------------------------------------------------------------
__global__ __launch_bounds__(256) void chunkscan_kernel(
    float* __restrict__ states, const float* __restrict__ Acs)
{
    int idx = blockIdx.x * 256 + threadIdx.x;  // BATCH*NHEADS*HEADDIM*D_STATE
    int pn  = idx % (HEADDIM * D_STATE);
    int bh  = idx / (HEADDIM * D_STATE);
    int h   = bh % NHEADS;
    int b   = bh / NHEADS;
    float carry = 0.f;
    for (int c = 0; c < NC; c++) {
        int bch = (b * NC + c) * NHEADS + h;
        size_t off = (size_t)bch * HEADDIM * D_STATE + pn;
        float s   = states[off];
        states[off] = carry;                       // prev-state for this chunk
        float dec = expf(Acs[(size_t)bch * CHUNK + CHUNK - 1]);
        carry = carry * dec + s;
    }
}

// ---------------------------------------------------------------------------
// Y = causal (CB ∘ L) @ (x*dt)  +  exp(Acs) * C @ prev^T     per (b,c,h,p-half)
// ---------------------------------------------------------------------------
__global__ __launch_bounds__(256) void y_kernel(
    const bf16* __restrict__ xbc, const float* __restrict__ dtsp,
    const float* __restrict__ Acs, const float* __restrict__ CBm,
    const float* __restrict__ prev, bf16* __restrict__ Y)
{
    int blk  = blockIdx.x;
    int ph   = blk & 1;
    int bch  = blk >> 1;
    int h    = bch % NHEADS;
    int bc   = bch / NHEADS;
    int row0 = bc * CHUNK;
    int p0   = ph * 64;
    int q    = threadIdx.x;

    __shared__ float sAcs[CHUNK];
    __shared__ float sdt[CHUNK];
    __shared__ float prevs[64][D_STATE];  // [p][n]
    __shared__ float xs[64][64];

    sAcs[q] = Acs[(size_t)bch * CHUNK + q];
    sdt[q]  = dtsp[(size_t)(row0 + q) * NHEADS + h];
    for (int i = q; i < 64 * D_STATE; i += 256) {
        int p = i / D_STATE, n = i % D_STATE;
        prevs[p][n] = prev[(size_t)bch * HEADDIM * D_STATE + (size_t)(p0 + p) * D_STATE + n];
    }
    __syncthreads();

    float acc[64];
#pragma unroll
    for (int p = 0; p < 64; p++) acc[p] = 0.f;

    // ----- inter-chunk (prev-state) contribution -----
    float eq = expf(sAcs[q]);
    const bf16* Crow = xbc + (size_t)(row0 + q) * CONV_DIM + D_INNER + D_STATE;
    for (int n = 0; n < D_STATE; n++) {
        float cqn = __bfloat162float(Crow[n]) * eq;
#pragma unroll
        for (int p = 0; p < 64; p++) acc[p] += cqn * prevs[p][n];
    }

    // ----- intra-chunk (diagonal, causal) contribution -----
    const float* CBrow = CBm + (size_t)bc * CHUNK * CHUNK + (size_t)q * CHUNK;
    float aq = sAcs[q];
    for (int s0 = 0; s0 < CHUNK; s0 += 64) {
        __syncthreads();
        for (int i = q; i < 64 * 64; i += 256) {
            int k = i / 64, p = i % 64;
            int row = row0 + s0 + k;
            xs[k][p] = __bfloat162float(xbc[(size_t)row * CONV_DIM + h * HEADDIM + p0 + p]);
        }
        __syncthreads();
        int smax = min(64, q - s0 + 1);
        for (int k = 0; k < smax; k++) {
            int s = s0 + k;
            float w = CBrow[s] * expf(aq - sAcs[s]) * sdt[s];
#pragma unroll
            for (int p = 0; p < 64; p++) acc[p] += w * xs[k][p];
        }
    }

    bf16* Yrow = Y + (size_t)(row0 + q) * D_INNER + h * HEADDIM + p0;
#pragma unroll
    for (int p = 0; p < 64; p++) stf(&Yrow[p], acc[p]);
}

// ---------------------------------------------------------------------------
// y = (Y + D*x) * silu(z);  RMSNorm over D_INNER; in-place on Y (bf16)
// ---------------------------------------------------------------------------
__global__ __launch_bounds__(256) void gate_norm_kernel(
    bf16* __restrict__ Yio, const bf16* __restrict__ zx,
    const bf16* __restrict__ xbc, const float* __restrict__ Dv,
    const float* __restrict__ nw)
{
    int row = blockIdx.x;
    int t   = threadIdx.x;
    float vals[8];
    float ss = 0.f;
#pragma unroll
    for (int j = 0; j < 8; j++) {
        int d = t + 256 * j;
        float y = __bfloat162float(Yio[(size_t)row * D_INNER + d]) +
                  Dv[d >> 7] * __bfloat162float(xbc[(size_t)row * CONV_DIM + d]);
        float z = __bfloat162float(zx[(size_t)row * DIM_IN_PROJ + d]);
        y *= z * sigmoidf_(z);
        vals[j] = y;
        ss += y * y;
    }
    __shared__ float red[256];
    red[t] = ss;
    __syncthreads();
    for (int o = 128; o > 0; o >>= 1) {
        if (t < o) red[t] += red[t + o];
        __syncthreads();
    }
    float rms = rsqrtf(red[0] / (float)D_INNER + EPS);
#pragma unroll
    for (int j = 0; j < 8; j++) {
        int d = t + 256 * j;
        stf(&Yio[(size_t)row * D_INNER + d], vals[j] * rms * nw[d]);
    }
}

// ---------------------------------------------------------------------------
extern "C" void kernel_launch(void* const* d_in, const int* in_sizes, int n_in,
                              void* d_out, int out_size, void* d_ws, size_t ws_size,
                              hipStream_t stream)
{
    const float* u       = (const float*)d_in[0];
    const float* W_in    = (const float*)d_in[1];
    const float* conv_w  = (const float*)d_in[2];
    const float* conv_b  = (const float*)d_in[3];
    const float* dt_bias = (const float*)d_in[4];
    const float* A_log   = (const float*)d_in[5];
    const float* Dv      = (const float*)d_in[6];
    const float* norm_w  = (const float*)d_in[7];
    const float* W_out   = (const float*)d_in[8];
    float* out = (float*)d_out;

    // ---- workspace layout (bytes, 256-aligned), total ~178 MB ----
    char* base = (char*)d_ws;
    size_t off = 0;
    auto alloc = [&](size_t bytes) -> char* {
        char* p = base + off;
        off += (bytes + 255) & ~(size_t)255;
        return p;
    };
    bf16*  zxb    = (bf16*) alloc((size_t)ROWS * DIM_IN_PROJ * 2);                      // 71.5 MB
    bf16*  xbc    = (bf16*) alloc((size_t)ROWS * CONV_DIM * 2);                         // 37.7 MB
    float* dtraw  = (float*)alloc((size_t)ROWS * NHEADS * 4);                           //  0.5 MB
    float* dtsp   = (float*)alloc((size_t)ROWS * NHEADS * 4);                           //  0.5 MB
    float* Acs    = (float*)alloc((size_t)BATCH * NC * NHEADS * CHUNK * 4);             //  0.5 MB
    float* states = (float*)alloc((size_t)BATCH * NC * NHEADS * HEADDIM * D_STATE * 4); // 33.5 MB
    float* CBm    = (float*)alloc((size_t)BATCH * NC * CHUNK * CHUNK * 4);              //  8.4 MB
    bf16*  Y      = (bf16*) alloc((size_t)ROWS * D_INNER * 2);                          // 33.5 MB
    if (off > ws_size) return;   // scratch too small: fail cleanly (poison stays in d_out)

    // 1. in-projection: zxb = bf16( u @ W_in^T )   (8192 x 4368 x 1024)
    gemm_abt<float, float, bf16, 64, 64, 16, 4, 4>
        <<<dim3((DIM_IN_PROJ + 63) / 64, ROWS / 64, 1), 256, 0, stream>>>(
        u, W_in, zxb, ROWS, DIM_IN_PROJ, D_MODEL, D_MODEL, D_MODEL, DIM_IN_PROJ, 0, 0, 0);

    // 1b. dt columns re-projected in fp32 (last 16 rows of W_in)
    gemm_abt<float, float, float, 64, 64, 16, 4, 4>
        <<<dim3(1, ROWS / 64, 1), 256, 0, stream>>>(
        u, W_in + (size_t)(D_INNER + CONV_DIM) * D_MODEL, dtraw,
        ROWS, NHEADS, D_MODEL, D_MODEL, D_MODEL, NHEADS, 0, 0, 0);

    // 2. conv + SiLU
    conv_silu_kernel<<<(ROWS * CONV_DIM) / 256, 256, 0, stream>>>(zxb, conv_w, conv_b, xbc);

    // 3. dt softplus
    dt_softplus_kernel<<<(ROWS * NHEADS) / 256, 256, 0, stream>>>(dtraw, dt_bias, dtsp);

    // 4. cumsum of dA
    cumsum_kernel<<<BATCH * NC * NHEADS, 256, 0, stream>>>(dtsp, A_log, Acs);

    // 5. chunk states
    states_kernel<<<BATCH * NC * NHEADS, 256, 0, stream>>>(xbc, dtsp, Acs, states);

    // 6. inter-chunk scan (in place: states[c] becomes prev-state of chunk c)
    chunkscan_kernel<<<(BATCH * NHEADS * HEADDIM * D_STATE) / 256, 256, 0, stream>>>(
        states, Acs);

    // 7. CB = C @ B^T per (b,c)   (batched 256 x 256 x 128)
    gemm_abt<bf16, bf16, float, 64, 64, 16, 4, 4>
        <<<dim3(4, 4, BATCH * NC), 256, 0, stream>>>(
        xbc + D_INNER + D_STATE, xbc + D_INNER, CBm,
        CHUNK, CHUNK, D_STATE, CONV_DIM, CONV_DIM, CHUNK,
        (long long)CHUNK * CONV_DIM, (long long)CHUNK * CONV_DIM, (long long)CHUNK * CHUNK);

    // 8. Y = diag + off contributions
    y_kernel<<<BATCH * NC * NHEADS * 2, 256, 0, stream>>>(xbc, dtsp, Acs, CBm, states, Y);

    // 9. gate + RMSNorm (in-place on Y)
    gate_norm_kernel<<<ROWS, 256, 0, stream>>>(Y, zxb, xbc, Dv, norm_w);

    // 10. out-projection: out = Y @ W_out^T   (8192 x 1024 x 2048)
    gemm_abt<bf16, float, float, 64, 64, 16, 4, 4>
        <<<dim3(D_MODEL / 64, ROWS / 64, 1), 256, 0, stream>>>(
        Y, W_out, out, ROWS, D_MODEL, D_INNER, D_INNER, D_INNER, D_MODEL, 0, 0, 0);
}

// Round 3
// 980.599 us; speedup vs baseline: 3.3400x; 3.3400x over previous
//
#include <hip/hip_runtime.h>
#include <hip/hip_bf16.h>
#include <cstddef>
#include <cstdint>

#define D_MODEL     1024
#define D_INNER     2048
#define D_STATE     128
#define NHEADS      16
#define HEADDIM     128
#define D_CONV      4
#define CHUNK       256
#define CONV_DIM    2304      // D_INNER + 2*D_STATE
#define DIM_IN_PROJ 4368      // 2*D_INNER + 2*D_STATE + NHEADS
#define NPAD_WIN    4480      // 35*128, zero-padded W_in rows for MFMA tiling
#define BATCH       2
#define SEQ         4096
#define ROWS        8192      // BATCH*SEQ
#define NC          16        // SEQ/CHUNK
#define EPS         1e-5f

typedef __hip_bfloat16 bf16;
typedef __attribute__((ext_vector_type(8))) short bf16x8;
typedef __attribute__((ext_vector_type(4))) float f32x4;

__device__ __forceinline__ float sigmoidf_(float x) { return 1.f / (1.f + expf(-x)); }

__device__ __forceinline__ float ldf(const float* p) { return *p; }
__device__ __forceinline__ float ldf(const bf16* p)  { return __bfloat162float(*p); }
__device__ __forceinline__ void  stf(float* p, float v) { *p = v; }
__device__ __forceinline__ void  stf(bf16* p, float v)  { *p = __float2bfloat16(v); }

#define GLOAD_LDS16(gp, lp) \
    __builtin_amdgcn_global_load_lds((const __attribute__((address_space(1))) unsigned int*)(gp), \
        (__attribute__((address_space(3))) unsigned int*)(lp), 16, 0, 0)

// ---------------------------------------------------------------------------
// MFMA bf16 GEMM:  C[M][N] = A[M][K] * B[N][K]^T    (m97 structure)
// 128x128 tile, BK=32, 4 waves x (4x4 frags of 16x16x32), global_load_lds.
// Requires: M%128==0, K%32==0, staged B rows exist up to col0+127 (pad B).
// ---------------------------------------------------------------------------
template<typename TC>
__global__ __launch_bounds__(256) void gemm_mfma_bt(
    const bf16* __restrict__ A, const bf16* __restrict__ B, TC* __restrict__ C,
    int M, int N, int K, int lda, int ldb, int ldc,
    long long sA, long long sB, long long sC)
{
    A += (long long)blockIdx.z * sA;
    B += (long long)blockIdx.z * sB;
    C += (long long)blockIdx.z * sC;

    __shared__ bf16 As[128 * 32];
    __shared__ bf16 Bs[128 * 32];

    const int tid  = threadIdx.x;
    const int lane = tid & 63;
    const int wave = tid >> 6;
    const int wr   = wave >> 1;        // 0..1
    const int wc   = wave & 1;         // 0..1
    const int row0 = blockIdx.y * 128;
    const int col0 = blockIdx.x * 128;
    const int l15  = lane & 15;
    const int l4   = lane >> 4;        // 0..3

    // staging map: thread t stages 16B = 8 bf16; row = t/4, col octet = t%4
    const int srow = tid >> 2;         // 0..63
    const int scol = (tid & 3) * 8;    // element column

    f32x4 acc[4][4];
#pragma unroll
    for (int m = 0; m < 4; m++)
#pragma unroll
        for (int n = 0; n < 4; n++) acc[m][n] = (f32x4){0.f, 0.f, 0.f, 0.f};

    for (int k0 = 0; k0 < K; k0 += 32) {
        const bf16* gA0 = A + (size_t)(row0 + srow) * lda + k0 + scol;
        const bf16* gA1 = A + (size_t)(row0 + 64 + srow) * lda + k0 + scol;
        const bf16* gB0 = B + (size_t)(col0 + srow) * ldb + k0 + scol;
        const bf16* gB1 = B + (size_t)(col0 + 64 + srow) * ldb + k0 + scol;
        GLOAD_LDS16(gA0, &As[tid * 8]);
        GLOAD_LDS16(gA1, &As[2048 + tid * 8]);
        GLOAD_LDS16(gB0, &Bs[tid * 8]);
        GLOAD_LDS16(gB1, &Bs[2048 + tid * 8]);
        __syncthreads();   // drains vmcnt: LDS tiles complete

        bf16x8 af[4], bg[4];
#pragma unroll
        for (int m = 0; m < 4; m++) {
            int r = wr * 64 + m * 16 + l15;
            af[m] = *reinterpret_cast<const bf16x8*>(&As[r * 32 + l4 * 8]);
        }
#pragma unroll
        for (int n = 0; n < 4; n++) {
            int r = wc * 64 + n * 16 + l15;
            bg[n] = *reinterpret_cast<const bf16x8*>(&Bs[r * 32 + l4 * 8]);
        }
#pragma unroll
        for (int m = 0; m < 4; m++)
#pragma unroll
            for (int n = 0; n < 4; n++)
                acc[m][n] = __builtin_amdgcn_mfma_f32_16x16x32_bf16(af[m], bg[n], acc[m][n], 0, 0, 0);
        __syncthreads();   // all waves done reading before next overwrite
    }

    // C/D layout: col = lane&15, row = (lane>>4)*4 + j   [m89/m91 verified]
#pragma unroll
    for (int m = 0; m < 4; m++) {
        int grb = row0 + wr * 64 + m * 16 + l4 * 4;
#pragma unroll
        for (int n = 0; n < 4; n++) {
            int gc = col0 + wc * 64 + n * 16 + l15;
            if (gc < N) {
#pragma unroll
                for (int j = 0; j < 4; j++) {
                    int gr = grb + j;
                    if (gr < M) stf(&C[(size_t)gr * ldc + gc], acc[m][n][j]);
                }
            }
        }
    }
}

// ---------------------------------------------------------------------------
// fp32 -> bf16 cast (vectorized, n%4==0)
// ---------------------------------------------------------------------------
__global__ __launch_bounds__(256) void cast_bf16_kernel(
    const float4* __restrict__ src, ushort4* __restrict__ dst, int n4)
{
    int i = blockIdx.x * 256 + threadIdx.x;
    if (i >= n4) return;
    float4 v = src[i];
    ushort4 o;
    bf16 h;
    h = __float2bfloat16(v.x); o.x = *reinterpret_cast<unsigned short*>(&h);
    h = __float2bfloat16(v.y); o.y = *reinterpret_cast<unsigned short*>(&h);
    h = __float2bfloat16(v.z); o.z = *reinterpret_cast<unsigned short*>(&h);
    h = __float2bfloat16(v.w); o.w = *reinterpret_cast<unsigned short*>(&h);
    dst[i] = o;
}

// fp32 -> bf16 cast of W_in with zero-pad to NPAD_WIN rows
__global__ __launch_bounds__(256) void cast_win_kernel(
    const float4* __restrict__ src, ushort4* __restrict__ dst)
{
    int i = blockIdx.x * 256 + threadIdx.x;     // over NPAD_WIN*1024/4
    if (i >= NPAD_WIN * D_MODEL / 4) return;
    int row = (i * 4) / D_MODEL;
    ushort4 o = {0, 0, 0, 0};
    if (row < DIM_IN_PROJ) {
        float4 v = src[i];
        bf16 h;
        h = __float2bfloat16(v.x); o.x = *reinterpret_cast<unsigned short*>(&h);
        h = __float2bfloat16(v.y); o.y = *reinterpret_cast<unsigned short*>(&h);
        h = __float2bfloat16(v.z); o.z = *reinterpret_cast<unsigned short*>(&h);
        h = __float2bfloat16(v.w); o.w = *reinterpret_cast<unsigned short*>(&h);
    }
    dst[i] = o;
}

// ---------------------------------------------------------------------------
// Naive fp32 GEMM (kept for the small dt projection; full-precision chain)
// ---------------------------------------------------------------------------
template<typename TA, typename TB, typename TC, int BM, int BN, int BK, int TM, int TN>
__global__ __launch_bounds__(256) void gemm_abt(
    const TA* __restrict__ A, const TB* __restrict__ B, TC* __restrict__ C,
    int M, int N, int K, int lda, int ldb, int ldc,
    long long sA, long long sB, long long sC)
{
    A += (long long)blockIdx.z * sA;
    B += (long long)blockIdx.z * sB;
    C += (long long)blockIdx.z * sC;

    __shared__ float Asm[BK][BM + 1];
    __shared__ float Bsm[BK][BN + 1];

    const int tid  = threadIdx.x;
    const int row0 = blockIdx.y * BM;
    const int col0 = blockIdx.x * BN;
    const int tx   = tid % (BN / TN);
    const int ty   = tid / (BN / TN);

    float acc[TM][TN];
#pragma unroll
    for (int i = 0; i < TM; i++)
#pragma unroll
        for (int j = 0; j < TN; j++) acc[i][j] = 0.f;

    for (int k0 = 0; k0 < K; k0 += BK) {
        for (int i = tid; i < BM * BK; i += 256) {
            int m = i / BK, k = i % BK;
            int gm = row0 + m;
            Asm[k][m] = (gm < M) ? ldf(&A[(size_t)gm * lda + k0 + k]) : 0.f;
        }
        for (int i = tid; i < BN * BK; i += 256) {
            int n = i / BK, k = i % BK;
            int gn = col0 + n;
            Bsm[k][n] = (gn < N) ? ldf(&B[(size_t)gn * ldb + k0 + k]) : 0.f;
        }
        __syncthreads();
#pragma unroll
        for (int k = 0; k < BK; k++) {
            float a[TM], bb[TN];
#pragma unroll
            for (int i = 0; i < TM; i++) a[i] = Asm[k][ty * TM + i];
#pragma unroll
            for (int j = 0; j < TN; j++) bb[j] = Bsm[k][tx * TN + j];
#pragma unroll
            for (int i = 0; i < TM; i++)
#pragma unroll
                for (int j = 0; j < TN; j++) acc[i][j] += a[i] * bb[j];
        }
        __syncthreads();
    }
#pragma unroll
    for (int i = 0; i < TM; i++) {
        int gm = row0 + ty * TM + i;
        if (gm >= M) continue;
#pragma unroll
        for (int j = 0; j < TN; j++) {
            int gn = col0 + tx * TN + j;
            if (gn < N) stf(&C[(size_t)gm * ldc + gn], acc[i][j]);
        }
    }
}

// ---------------------------------------------------------------------------
// Depthwise causal conv (width 4) + bias + SiLU on the xBC slice of zxbcdt
// ---------------------------------------------------------------------------
__global__ __launch_bounds__(256) void conv_silu_kernel(
    const bf16* __restrict__ zx, const float* __restrict__ cw,
    const float* __restrict__ cb, bf16* __restrict__ xbc)
{
    int idx = blockIdx.x * 256 + threadIdx.x;
    if (idx >= ROWS * CONV_DIM) return;
    int c   = idx % CONV_DIM;
    int row = idx / CONV_DIM;
    int l   = row & (SEQ - 1);
    float acc = cb[c];
#pragma unroll
    for (int k = 0; k < D_CONV; k++) {
        int ls = l - (D_CONV - 1) + k;
        if (ls >= 0)
            acc += cw[c * D_CONV + k] *
                   __bfloat162float(zx[(size_t)(row - (D_CONV - 1) + k) * DIM_IN_PROJ + D_INNER + c]);
    }
    stf(&xbc[(size_t)row * CONV_DIM + c], acc * sigmoidf_(acc));
}

// ---------------------------------------------------------------------------
__global__ __launch_bounds__(256) void dt_softplus_kernel(
    const float* __restrict__ dtraw, const float* __restrict__ dt_bias,
    float* __restrict__ dtsp)
{
    int idx = blockIdx.x * 256 + threadIdx.x;   // ROWS*NHEADS
    if (idx >= ROWS * NHEADS) return;
    int h = idx % NHEADS;
    float x = dtraw[idx] + dt_bias[h];
    dtsp[idx] = (x > 20.f) ? x : log1pf(expf(x));
}

// ---------------------------------------------------------------------------
__global__ __launch_bounds__(256) void cumsum_kernel(
    const float* __restrict__ dtsp, const float* __restrict__ A_log,
    float* __restrict__ Acs)
{
    int blk = blockIdx.x;         // (b*NC+c)*NHEADS + h
    int h   = blk % NHEADS;
    int bc  = blk / NHEADS;
    int t   = threadIdx.x;
    int row = bc * CHUNK + t;
    float A = -expf(A_log[h]);
    __shared__ float buf[CHUNK];
    buf[t] = dtsp[(size_t)row * NHEADS + h] * A;
    __syncthreads();
    for (int off = 1; off < CHUNK; off <<= 1) {
        float v = (t >= off) ? buf[t - off] : 0.f;
        __syncthreads();
        buf[t] += v;
        __syncthreads();
    }
    Acs[(size_t)blk * CHUNK + t] = buf[t];
}

// ---------------------------------------------------------------------------
// Chunk states: states[h][p][n] = sum_q  g[q] * x[q,p] * B[q,n]
// ---------------------------------------------------------------------------
__global__ __launch_bounds__(256) void states_kernel(
    const bf16* __restrict__ xbc, const float* __restrict__ dtsp,
    const float* __restrict__ Acs, float* __restrict__ states)
{
    int blk  = blockIdx.x;  // bch
    int h    = blk % NHEADS;
    int bc   = blk / NHEADS;
    int row0 = bc * CHUNK;
    int tid  = threadIdx.x;

    __shared__ float g[CHUNK];
    __shared__ float Xs[16][HEADDIM];
    __shared__ float Bsh[16][D_STATE];

    {
        float last = Acs[(size_t)blk * CHUNK + CHUNK - 1];
        float a    = Acs[(size_t)blk * CHUNK + tid];
        g[tid] = dtsp[(size_t)(row0 + tid) * NHEADS + h] * expf(last - a);
    }
    __syncthreads();

    int tn = tid % 16, tp = tid / 16;
    float acc[8][8];
#pragma unroll
    for (int i = 0; i < 8; i++)
#pragma unroll
        for (int j = 0; j < 8; j++) acc[i][j] = 0.f;

    for (int q0 = 0; q0 < CHUNK; q0 += 16) {
        for (int i = tid; i < 16 * 128; i += 256) {
            int k = i / 128, p = i % 128;
            int row = row0 + q0 + k;
            Xs[k][p]  = __bfloat162float(xbc[(size_t)row * CONV_DIM + h * HEADDIM + p]) * g[q0 + k];
            Bsh[k][p] = __bfloat162float(xbc[(size_t)row * CONV_DIM + D_INNER + p]);
        }
        __syncthreads();
#pragma unroll
        for (int k = 0; k < 16; k++) {
            float a[8], b[8];
#pragma unroll
            for (int i = 0; i < 8; i++) a[i] = Xs[k][tp * 8 + i];
#pragma unroll
            for (int j = 0; j < 8; j++) b[j] = Bsh[k][tn * 8 + j];
#pragma unroll
            for (int i = 0; i < 8; i++)
#pragma unroll
                for (int j = 0; j < 8; j++) acc[i][j] += a[i] * b[j];
        }
        __syncthreads();
    }
#pragma unroll
    for (int i = 0; i < 8; i++)
#pragma unroll
        for (int j = 0; j < 8; j++)
            states[(size_t)blk * HEADDIM * D_STATE + (size_t)(tp * 8 + i) * D_STATE + tn * 8 + j]
                = acc[i][j];
}

// ---------------------------------------------------------------------------
// Sequential inter-chunk scan, IN PLACE on states
// ---------------------------------------------------------------------------
__global__ __launch_bounds__(256) void chunkscan_kernel(
    float* __restrict__ states, const float* __restrict__ Acs)
{
    int idx = blockIdx.x * 256 + threadIdx.x;  // BATCH*NHEADS*HEADDIM*D_STATE
    int pn  = idx % (HEADDIM * D_STATE);
    int bh  = idx / (HEADDIM * D_STATE);
    int h   = bh % NHEADS;
    int b   = bh / NHEADS;
    float carry = 0.f;
    for (int c = 0; c < NC; c++) {
        int bch = (b * NC + c) * NHEADS + h;
        size_t off = (size_t)bch * HEADDIM * D_STATE + pn;
        float s   = states[off];
        states[off] = carry;
        float dec = expf(Acs[(size_t)bch * CHUNK + CHUNK - 1]);
        carry = carry * dec + s;
    }
}

// ---------------------------------------------------------------------------
// Y = causal (CB ∘ L) @ (x*dt)  +  exp(Acs) * C @ prev^T     per (b,c,h,p-half)
// ---------------------------------------------------------------------------
__global__ __launch_bounds__(256) void y_kernel(
    const bf16* __restrict__ xbc, const float* __restrict__ dtsp,
    const float* __restrict__ Acs, const float* __restrict__ CBm,
    const float* __restrict__ prev, bf16* __restrict__ Y)
{
    int blk  = blockIdx.x;
    int ph   = blk & 1;
    int bch  = blk >> 1;
    int h    = bch % NHEADS;
    int bc   = bch / NHEADS;
    int row0 = bc * CHUNK;
    int p0   = ph * 64;
    int q    = threadIdx.x;

    __shared__ float sAcs[CHUNK];
    __shared__ float sdt[CHUNK];
    __shared__ float prevs[64][D_STATE];
    __shared__ float xs[64][64];

    sAcs[q] = Acs[(size_t)bch * CHUNK + q];
    sdt[q]  = dtsp[(size_t)(row0 + q) * NHEADS + h];
    for (int i = q; i < 64 * D_STATE; i += 256) {
        int p = i / D_STATE, n = i % D_STATE;
        prevs[p][n] = prev[(size_t)bch * HEADDIM * D_STATE + (size_t)(p0 + p) * D_STATE + n];
    }
    __syncthreads();

    float acc[64];
#pragma unroll
    for (int p = 0; p < 64; p++) acc[p] = 0.f;

    float eq = expf(sAcs[q]);
    const bf16* Crow = xbc + (size_t)(row0 + q) * CONV_DIM + D_INNER + D_STATE;
    for (int n = 0; n < D_STATE; n++) {
        float cqn = __bfloat162float(Crow[n]) * eq;
#pragma unroll
        for (int p = 0; p < 64; p++) acc[p] += cqn * prevs[p][n];
    }

    const float* CBrow = CBm + (size_t)bc * CHUNK * CHUNK + (size_t)q * CHUNK;
    float aq = sAcs[q];
    for (int s0 = 0; s0 < CHUNK; s0 += 64) {
        __syncthreads();
        for (int i = q; i < 64 * 64; i += 256) {
            int k = i / 64, p = i % 64;
            int row = row0 + s0 + k;
            xs[k][p] = __bfloat162float(xbc[(size_t)row * CONV_DIM + h * HEADDIM + p0 + p]);
        }
        __syncthreads();
        int smax = min(64, q - s0 + 1);
        for (int k = 0; k < smax; k++) {
            int s = s0 + k;
            float w = CBrow[s] * expf(aq - sAcs[s]) * sdt[s];
#pragma unroll
            for (int p = 0; p < 64; p++) acc[p] += w * xs[k][p];
        }
    }

    bf16* Yrow = Y + (size_t)(row0 + q) * D_INNER + h * HEADDIM + p0;
#pragma unroll
    for (int p = 0; p < 64; p++) stf(&Yrow[p], acc[p]);
}

// ---------------------------------------------------------------------------
// y = (Y + D*x) * silu(z);  RMSNorm over D_INNER; in-place on Y (bf16)
// ---------------------------------------------------------------------------
__global__ __launch_bounds__(256) void gate_norm_kernel(
    bf16* __restrict__ Yio, const bf16* __restrict__ zx,
    const bf16* __restrict__ xbc, const float* __restrict__ Dv,
    const float* __restrict__ nw)
{
    int row = blockIdx.x;
    int t   = threadIdx.x;
    float vals[8];
    float ss = 0.f;
#pragma unroll
    for (int j = 0; j < 8; j++) {
        int d = t + 256 * j;
        float y = __bfloat162float(Yio[(size_t)row * D_INNER + d]) +
                  Dv[d >> 7] * __bfloat162float(xbc[(size_t)row * CONV_DIM + d]);
        float z = __bfloat162float(zx[(size_t)row * DIM_IN_PROJ + d]);
        y *= z * sigmoidf_(z);
        vals[j] = y;
        ss += y * y;
    }
    __shared__ float red[256];
    red[t] = ss;
    __syncthreads();
    for (int o = 128; o > 0; o >>= 1) {
        if (t < o) red[t] += red[t + o];
        __syncthreads();
    }
    float rms = rsqrtf(red[0] / (float)D_INNER + EPS);
#pragma unroll
    for (int j = 0; j < 8; j++) {
        int d = t + 256 * j;
        stf(&Yio[(size_t)row * D_INNER + d], vals[j] * rms * nw[d]);
    }
}

// ---------------------------------------------------------------------------
extern "C" void kernel_launch(void* const* d_in, const int* in_sizes, int n_in,
                              void* d_out, int out_size, void* d_ws, size_t ws_size,
                              hipStream_t stream)
{
    const float* u       = (const float*)d_in[0];
    const float* W_in    = (const float*)d_in[1];
    const float* conv_w  = (const float*)d_in[2];
    const float* conv_b  = (const float*)d_in[3];
    const float* dt_bias = (const float*)d_in[4];
    const float* A_log   = (const float*)d_in[5];
    const float* Dv      = (const float*)d_in[6];
    const float* norm_w  = (const float*)d_in[7];
    const float* W_out   = (const float*)d_in[8];
    float* out = (float*)d_out;

    // ---- workspace layout (bytes, 256-aligned), total ~191 MB ----
    char* base = (char*)d_ws;
    size_t off = 0;
    auto alloc = [&](size_t bytes) -> char* {
        char* p = base + off;
        off += (bytes + 255) & ~(size_t)255;
        return p;
    };
    bf16*  zxb    = (bf16*) alloc((size_t)ROWS * DIM_IN_PROJ * 2);                      // 71.5 MB
    bf16*  xbc    = (bf16*) alloc((size_t)ROWS * CONV_DIM * 2);                         // 37.7 MB
    float* dtraw  = (float*)alloc((size_t)ROWS * NHEADS * 4);                           //  0.5 MB
    float* dtsp   = (float*)alloc((size_t)ROWS * NHEADS * 4);                           //  0.5 MB
    float* Acs    = (float*)alloc((size_t)BATCH * NC * NHEADS * CHUNK * 4);             //  0.5 MB
    float* states = (float*)alloc((size_t)BATCH * NC * NHEADS * HEADDIM * D_STATE * 4); // 33.5 MB
    float* CBm    = (float*)alloc((size_t)BATCH * NC * CHUNK * CHUNK * 4);              //  8.4 MB
    bf16*  Y      = (bf16*) alloc((size_t)ROWS * D_INNER * 2);                          // 33.5 MB
    bf16*  woutb  = (bf16*) alloc((size_t)D_MODEL * D_INNER * 2);                       //  4.2 MB
    // ub (16.8 MB) and winb (9.2 MB) alias the Y buffer: dead once y_kernel runs
    bf16*  ub     = Y;
    bf16*  winb   = Y + (size_t)ROWS * D_MODEL;
    if (off > ws_size) return;   // scratch too small: fail cleanly

    // 0. casts to bf16
    cast_bf16_kernel<<<(ROWS * D_MODEL / 4 + 255) / 256, 256, 0, stream>>>(
        (const float4*)u, (ushort4*)ub, ROWS * D_MODEL / 4);
    cast_win_kernel<<<(NPAD_WIN * D_MODEL / 4 + 255) / 256, 256, 0, stream>>>(
        (const float4*)W_in, (ushort4*)winb);
    cast_bf16_kernel<<<(D_MODEL * D_INNER / 4 + 255) / 256, 256, 0, stream>>>(
        (const float4*)W_out, (ushort4*)woutb, D_MODEL * D_INNER / 4);

    // 1. in-projection (MFMA): zxb = bf16(ub) @ winb^T   (8192 x 4368 x 1024)
    gemm_mfma_bt<bf16><<<dim3(NPAD_WIN / 128, ROWS / 128, 1), 256, 0, stream>>>(
        ub, winb, zxb, ROWS, DIM_IN_PROJ, D_MODEL, D_MODEL, D_MODEL, DIM_IN_PROJ, 0, 0, 0);

    // 1b. dt columns re-projected in fp32 (full-precision exponent chain)
    gemm_abt<float, float, float, 64, 64, 16, 4, 4>
        <<<dim3(1, ROWS / 64, 1), 256, 0, stream>>>(
        u, W_in + (size_t)(D_INNER + CONV_DIM) * D_MODEL, dtraw,
        ROWS, NHEADS, D_MODEL, D_MODEL, D_MODEL, NHEADS, 0, 0, 0);

    // 2. conv + SiLU
    conv_silu_kernel<<<(ROWS * CONV_DIM) / 256, 256, 0, stream>>>(zxb, conv_w, conv_b, xbc);

    // 3. dt softplus
    dt_softplus_kernel<<<(ROWS * NHEADS) / 256, 256, 0, stream>>>(dtraw, dt_bias, dtsp);

    // 4. cumsum of dA
    cumsum_kernel<<<BATCH * NC * NHEADS, 256, 0, stream>>>(dtsp, A_log, Acs);

    // 5. chunk states
    states_kernel<<<BATCH * NC * NHEADS, 256, 0, stream>>>(xbc, dtsp, Acs, states);

    // 6. inter-chunk scan (in place)
    chunkscan_kernel<<<(BATCH * NHEADS * HEADDIM * D_STATE) / 256, 256, 0, stream>>>(
        states, Acs);

    // 7. CB = C @ B^T per (b,c) (MFMA, batched 256 x 256 x 128)
    gemm_mfma_bt<float><<<dim3(2, 2, BATCH * NC), 256, 0, stream>>>(
        xbc + D_INNER + D_STATE, xbc + D_INNER, CBm,
        CHUNK, CHUNK, D_STATE, CONV_DIM, CONV_DIM, CHUNK,
        (long long)CHUNK * CONV_DIM, (long long)CHUNK * CONV_DIM, (long long)CHUNK * CHUNK);

    // 8. Y = diag + off contributions  (overwrites ub/winb alias region — now dead)
    y_kernel<<<BATCH * NC * NHEADS * 2, 256, 0, stream>>>(xbc, dtsp, Acs, CBm, states, Y);

    // 9. gate + RMSNorm (in-place on Y)
    gate_norm_kernel<<<ROWS, 256, 0, stream>>>(Y, zxb, xbc, Dv, norm_w);

    // 10. out-projection (MFMA): out = Y @ woutb^T   (8192 x 1024 x 2048)
    gemm_mfma_bt<float><<<dim3(D_MODEL / 128, ROWS / 128, 1), 256, 0, stream>>>(
        Y, woutb, out, ROWS, D_MODEL, D_INNER, D_INNER, D_INNER, D_MODEL, 0, 0, 0);
}

// Round 4
// 530.444 us; speedup vs baseline: 6.1745x; 1.8486x over previous
//
#include <hip/hip_runtime.h>
#include <hip/hip_bf16.h>
#include <cstddef>
#include <cstdint>

#define D_MODEL     1024
#define D_INNER     2048
#define D_STATE     128
#define NHEADS      16
#define HEADDIM     128
#define D_CONV      4
#define CHUNK       256
#define CONV_DIM    2304      // D_INNER + 2*D_STATE
#define DIM_IN_PROJ 4368      // 2*D_INNER + 2*D_STATE + NHEADS
#define NPAD_WIN    4480      // 35*128, zero-padded W_in rows for MFMA tiling
#define BATCH       2
#define SEQ         4096
#define ROWS        8192      // BATCH*SEQ
#define NC          16        // SEQ/CHUNK
#define EPS         1e-5f

typedef __hip_bfloat16 bf16;
typedef __attribute__((ext_vector_type(8))) short bf16x8;
typedef __attribute__((ext_vector_type(4))) float f32x4;

__device__ __forceinline__ float sigmoidf_(float x) { return 1.f / (1.f + expf(-x)); }

__device__ __forceinline__ float ldf(const float* p) { return *p; }
__device__ __forceinline__ float ldf(const bf16* p)  { return __bfloat162float(*p); }
__device__ __forceinline__ void  stf(float* p, float v) { *p = v; }
__device__ __forceinline__ void  stf(bf16* p, float v)  { *p = __float2bfloat16(v); }

__device__ __forceinline__ short f2bs(float x) {            // float -> bf16 bits (RNE)
    bf16 h = __float2bfloat16(x);
    return __builtin_bit_cast(short, h);
}
__device__ __forceinline__ float bs2f(short s) {            // bf16 bits -> float
    unsigned int u = ((unsigned int)(unsigned short)s) << 16;
    return __builtin_bit_cast(float, u);
}

#define GLOAD_LDS16(gp, lp) \
    __builtin_amdgcn_global_load_lds((const __attribute__((address_space(1))) unsigned int*)(gp), \
        (__attribute__((address_space(3))) unsigned int*)(lp), 16, 0, 0)

// ---------------------------------------------------------------------------
// MFMA bf16 GEMM:  C[M][N] = A[M][K] * B[N][K]^T    (m97 structure)
// ---------------------------------------------------------------------------
template<typename TC>
__global__ __launch_bounds__(256) void gemm_mfma_bt(
    const bf16* __restrict__ A, const bf16* __restrict__ B, TC* __restrict__ C,
    int M, int N, int K, int lda, int ldb, int ldc,
    long long sA, long long sB, long long sC)
{
    A += (long long)blockIdx.z * sA;
    B += (long long)blockIdx.z * sB;
    C += (long long)blockIdx.z * sC;

    __shared__ bf16 As[128 * 32];
    __shared__ bf16 Bs[128 * 32];

    const int tid  = threadIdx.x;
    const int lane = tid & 63;
    const int wave = tid >> 6;
    const int wr   = wave >> 1;
    const int wc   = wave & 1;
    const int row0 = blockIdx.y * 128;
    const int col0 = blockIdx.x * 128;
    const int l15  = lane & 15;
    const int l4   = lane >> 4;

    const int srow = tid >> 2;
    const int scol = (tid & 3) * 8;

    f32x4 acc[4][4];
#pragma unroll
    for (int m = 0; m < 4; m++)
#pragma unroll
        for (int n = 0; n < 4; n++) acc[m][n] = (f32x4){0.f, 0.f, 0.f, 0.f};

    for (int k0 = 0; k0 < K; k0 += 32) {
        const bf16* gA0 = A + (size_t)(row0 + srow) * lda + k0 + scol;
        const bf16* gA1 = A + (size_t)(row0 + 64 + srow) * lda + k0 + scol;
        const bf16* gB0 = B + (size_t)(col0 + srow) * ldb + k0 + scol;
        const bf16* gB1 = B + (size_t)(col0 + 64 + srow) * ldb + k0 + scol;
        GLOAD_LDS16(gA0, &As[tid * 8]);
        GLOAD_LDS16(gA1, &As[2048 + tid * 8]);
        GLOAD_LDS16(gB0, &Bs[tid * 8]);
        GLOAD_LDS16(gB1, &Bs[2048 + tid * 8]);
        __syncthreads();

        bf16x8 af[4], bg[4];
#pragma unroll
        for (int m = 0; m < 4; m++) {
            int r = wr * 64 + m * 16 + l15;
            af[m] = *reinterpret_cast<const bf16x8*>(&As[r * 32 + l4 * 8]);
        }
#pragma unroll
        for (int n = 0; n < 4; n++) {
            int r = wc * 64 + n * 16 + l15;
            bg[n] = *reinterpret_cast<const bf16x8*>(&Bs[r * 32 + l4 * 8]);
        }
#pragma unroll
        for (int m = 0; m < 4; m++)
#pragma unroll
            for (int n = 0; n < 4; n++)
                acc[m][n] = __builtin_amdgcn_mfma_f32_16x16x32_bf16(af[m], bg[n], acc[m][n], 0, 0, 0);
        __syncthreads();
    }

#pragma unroll
    for (int m = 0; m < 4; m++) {
        int grb = row0 + wr * 64 + m * 16 + l4 * 4;
#pragma unroll
        for (int n = 0; n < 4; n++) {
            int gc = col0 + wc * 64 + n * 16 + l15;
            if (gc < N) {
#pragma unroll
                for (int j = 0; j < 4; j++) {
                    int gr = grb + j;
                    if (gr < M) stf(&C[(size_t)gr * ldc + gc], acc[m][n][j]);
                }
            }
        }
    }
}

// ---------------------------------------------------------------------------
// casts
// ---------------------------------------------------------------------------
__global__ __launch_bounds__(256) void cast_bf16_kernel(
    const float4* __restrict__ src, ushort4* __restrict__ dst, int n4)
{
    int i = blockIdx.x * 256 + threadIdx.x;
    if (i >= n4) return;
    float4 v = src[i];
    ushort4 o;
    o.x = (unsigned short)f2bs(v.x);
    o.y = (unsigned short)f2bs(v.y);
    o.z = (unsigned short)f2bs(v.z);
    o.w = (unsigned short)f2bs(v.w);
    dst[i] = o;
}

__global__ __launch_bounds__(256) void cast_win_kernel(
    const float4* __restrict__ src, ushort4* __restrict__ dst)
{
    int i = blockIdx.x * 256 + threadIdx.x;
    if (i >= NPAD_WIN * D_MODEL / 4) return;
    int row = (i * 4) / D_MODEL;
    ushort4 o = {0, 0, 0, 0};
    if (row < DIM_IN_PROJ) {
        float4 v = src[i];
        o.x = (unsigned short)f2bs(v.x);
        o.y = (unsigned short)f2bs(v.y);
        o.z = (unsigned short)f2bs(v.z);
        o.w = (unsigned short)f2bs(v.w);
    }
    dst[i] = o;
}

// ---------------------------------------------------------------------------
// Naive fp32 GEMM (small dt projection only)
// ---------------------------------------------------------------------------
template<typename TA, typename TB, typename TC, int BM, int BN, int BK, int TM, int TN>
__global__ __launch_bounds__(256) void gemm_abt(
    const TA* __restrict__ A, const TB* __restrict__ B, TC* __restrict__ C,
    int M, int N, int K, int lda, int ldb, int ldc,
    long long sA, long long sB, long long sC)
{
    A += (long long)blockIdx.z * sA;
    B += (long long)blockIdx.z * sB;
    C += (long long)blockIdx.z * sC;

    __shared__ float Asm[BK][BM + 1];
    __shared__ float Bsm[BK][BN + 1];

    const int tid  = threadIdx.x;
    const int row0 = blockIdx.y * BM;
    const int col0 = blockIdx.x * BN;
    const int tx   = tid % (BN / TN);
    const int ty   = tid / (BN / TN);

    float acc[TM][TN];
#pragma unroll
    for (int i = 0; i < TM; i++)
#pragma unroll
        for (int j = 0; j < TN; j++) acc[i][j] = 0.f;

    for (int k0 = 0; k0 < K; k0 += BK) {
        for (int i = tid; i < BM * BK; i += 256) {
            int m = i / BK, k = i % BK;
            int gm = row0 + m;
            Asm[k][m] = (gm < M) ? ldf(&A[(size_t)gm * lda + k0 + k]) : 0.f;
        }
        for (int i = tid; i < BN * BK; i += 256) {
            int n = i / BK, k = i % BK;
            int gn = col0 + n;
            Bsm[k][n] = (gn < N) ? ldf(&B[(size_t)gn * ldb + k0 + k]) : 0.f;
        }
        __syncthreads();
#pragma unroll
        for (int k = 0; k < BK; k++) {
            float a[TM], bb[TN];
#pragma unroll
            for (int i = 0; i < TM; i++) a[i] = Asm[k][ty * TM + i];
#pragma unroll
            for (int j = 0; j < TN; j++) bb[j] = Bsm[k][tx * TN + j];
#pragma unroll
            for (int i = 0; i < TM; i++)
#pragma unroll
                for (int j = 0; j < TN; j++) acc[i][j] += a[i] * bb[j];
        }
        __syncthreads();
    }
#pragma unroll
    for (int i = 0; i < TM; i++) {
        int gm = row0 + ty * TM + i;
        if (gm >= M) continue;
#pragma unroll
        for (int j = 0; j < TN; j++) {
            int gn = col0 + tx * TN + j;
            if (gn < N) stf(&C[(size_t)gm * ldc + gn], acc[i][j]);
        }
    }
}

// ---------------------------------------------------------------------------
// Depthwise causal conv (width 4) + bias + SiLU
// ---------------------------------------------------------------------------
__global__ __launch_bounds__(256) void conv_silu_kernel(
    const bf16* __restrict__ zx, const float* __restrict__ cw,
    const float* __restrict__ cb, bf16* __restrict__ xbc)
{
    int idx = blockIdx.x * 256 + threadIdx.x;
    if (idx >= ROWS * CONV_DIM) return;
    int c   = idx % CONV_DIM;
    int row = idx / CONV_DIM;
    int l   = row & (SEQ - 1);
    float acc = cb[c];
#pragma unroll
    for (int k = 0; k < D_CONV; k++) {
        int ls = l - (D_CONV - 1) + k;
        if (ls >= 0)
            acc += cw[c * D_CONV + k] *
                   __bfloat162float(zx[(size_t)(row - (D_CONV - 1) + k) * DIM_IN_PROJ + D_INNER + c]);
    }
    stf(&xbc[(size_t)row * CONV_DIM + c], acc * sigmoidf_(acc));
}

// ---------------------------------------------------------------------------
__global__ __launch_bounds__(256) void dt_softplus_kernel(
    const float* __restrict__ dtraw, const float* __restrict__ dt_bias,
    float* __restrict__ dtsp)
{
    int idx = blockIdx.x * 256 + threadIdx.x;
    if (idx >= ROWS * NHEADS) return;
    int h = idx % NHEADS;
    float x = dtraw[idx] + dt_bias[h];
    dtsp[idx] = (x > 20.f) ? x : log1pf(expf(x));
}

// ---------------------------------------------------------------------------
__global__ __launch_bounds__(256) void cumsum_kernel(
    const float* __restrict__ dtsp, const float* __restrict__ A_log,
    float* __restrict__ Acs)
{
    int blk = blockIdx.x;
    int h   = blk % NHEADS;
    int bc  = blk / NHEADS;
    int t   = threadIdx.x;
    int row = bc * CHUNK + t;
    float A = -expf(A_log[h]);
    __shared__ float buf[CHUNK];
    buf[t] = dtsp[(size_t)row * NHEADS + h] * A;
    __syncthreads();
    for (int off = 1; off < CHUNK; off <<= 1) {
        float v = (t >= off) ? buf[t - off] : 0.f;
        __syncthreads();
        buf[t] += v;
        __syncthreads();
    }
    Acs[(size_t)blk * CHUNK + t] = buf[t];
}

// ---------------------------------------------------------------------------
// states (MFMA): states[p][n] = sum_q xg[q,p] * B[q,n],  xg = x*dt*exp(alast-aq)
// One block per (b,c,h); 4 waves; both operands transposed through LDS.
// ---------------------------------------------------------------------------
__global__ __launch_bounds__(256, 2) void states_mfma_kernel(
    const bf16* __restrict__ xbc, const float* __restrict__ dtsp,
    const float* __restrict__ Acs, float* __restrict__ states)
{
    const int bch  = blockIdx.x;
    const int h    = bch % NHEADS;
    const int bc   = bch / NHEADS;
    const int row0 = bc * CHUNK;
    const int tid  = threadIdx.x;
    const int lane = tid & 63;
    const int wave = tid >> 6;
    const int l15  = lane & 15;
    const int l4   = lane >> 4;

    __shared__ float g[CHUNK];
    __shared__ bf16 xT[128 * 32];   // [p][q_local]
    __shared__ bf16 bT[128 * 32];   // [n][q_local]

    {
        float last = Acs[(size_t)bch * CHUNK + CHUNK - 1];
        float a    = Acs[(size_t)bch * CHUNK + tid];
        g[tid] = dtsp[(size_t)(row0 + tid) * NHEADS + h] * __expf(last - a);
    }

    const int sp0 = (tid & 15) * 8;     // col group (p or n)
    const int ssl = 2 * (tid >> 4);     // local q pair

    f32x4 acc[2][8];
#pragma unroll
    for (int m = 0; m < 2; m++)
#pragma unroll
        for (int n = 0; n < 8; n++) acc[m][n] = (f32x4){0.f, 0.f, 0.f, 0.f};

    for (int q0 = 0; q0 < CHUNK; q0 += 32) {
        __syncthreads();
        {
            const bf16* gx = xbc + (size_t)(row0 + q0 + ssl) * CONV_DIM + h * HEADDIM + sp0;
            bf16x8 v0 = *reinterpret_cast<const bf16x8*>(gx);
            bf16x8 v1 = *reinterpret_cast<const bf16x8*>(gx + CONV_DIM);
            const bf16* gb = xbc + (size_t)(row0 + q0 + ssl) * CONV_DIM + D_INNER + sp0;
            bf16x8 w0 = *reinterpret_cast<const bf16x8*>(gb);
            bf16x8 w1 = *reinterpret_cast<const bf16x8*>(gb + CONV_DIM);
            float g0 = g[q0 + ssl], g1 = g[q0 + ssl + 1];
#pragma unroll
            for (int j = 0; j < 8; j++) {
                unsigned int px = (unsigned short)f2bs(bs2f(v0[j]) * g0) |
                                  ((unsigned int)(unsigned short)f2bs(bs2f(v1[j]) * g1) << 16);
                *reinterpret_cast<unsigned int*>(&xT[(sp0 + j) * 32 + ssl]) = px;
                unsigned int pb = (unsigned short)w0[j] |
                                  ((unsigned int)(unsigned short)w1[j] << 16);
                *reinterpret_cast<unsigned int*>(&bT[(sp0 + j) * 32 + ssl]) = pb;
            }
        }
        __syncthreads();

        bf16x8 af[2], bg[8];
#pragma unroll
        for (int m = 0; m < 2; m++) {
            int p = wave * 32 + m * 16 + l15;
            af[m] = *reinterpret_cast<const bf16x8*>(&xT[p * 32 + l4 * 8]);
        }
#pragma unroll
        for (int n = 0; n < 8; n++) {
            int nn = n * 16 + l15;
            bg[n] = *reinterpret_cast<const bf16x8*>(&bT[nn * 32 + l4 * 8]);
        }
#pragma unroll
        for (int m = 0; m < 2; m++)
#pragma unroll
            for (int n = 0; n < 8; n++)
                acc[m][n] = __builtin_amdgcn_mfma_f32_16x16x32_bf16(af[m], bg[n], acc[m][n], 0, 0, 0);
    }

    float* sp = states + (size_t)bch * HEADDIM * D_STATE;
#pragma unroll
    for (int m = 0; m < 2; m++) {
        int pb = wave * 32 + m * 16 + l4 * 4;
#pragma unroll
        for (int n = 0; n < 8; n++) {
            int nn = n * 16 + l15;
#pragma unroll
            for (int j = 0; j < 4; j++)
                sp[(size_t)(pb + j) * D_STATE + nn] = acc[m][n][j];
        }
    }
}

// ---------------------------------------------------------------------------
// Sequential inter-chunk scan, IN PLACE on states
// ---------------------------------------------------------------------------
__global__ __launch_bounds__(256) void chunkscan_kernel(
    float* __restrict__ states, const float* __restrict__ Acs)
{
    int idx = blockIdx.x * 256 + threadIdx.x;
    int pn  = idx % (HEADDIM * D_STATE);
    int bh  = idx / (HEADDIM * D_STATE);
    int h   = bh % NHEADS;
    int b   = bh / NHEADS;
    float carry = 0.f;
    for (int c = 0; c < NC; c++) {
        int bch = (b * NC + c) * NHEADS + h;
        size_t off = (size_t)bch * HEADDIM * D_STATE + pn;
        float s   = states[off];
        states[off] = carry;
        float dec = expf(Acs[(size_t)bch * CHUNK + CHUNK - 1]);
        carry = carry * dec + s;
    }
}

// ---------------------------------------------------------------------------
// Y (MFMA): Y[q,p] = sum_{s<=q} CB[q,s]*exp(aq-as) * xdt[s,p]
//                  + sum_n C[q,n]*exp(aq) * prev[p,n]
// One block per (b,c,h); 4 waves; q-frags interleaved across waves for causal
// balance; xdt transposed through LDS; off-phase operands direct from global.
// ---------------------------------------------------------------------------
__global__ __launch_bounds__(256, 2) void y_mfma_kernel(
    const bf16* __restrict__ xbc, const float* __restrict__ dtsp,
    const float* __restrict__ Acs, const float* __restrict__ CBm,
    const float* __restrict__ prev, bf16* __restrict__ Y)
{
    const int bch  = blockIdx.x;
    const int h    = bch % NHEADS;
    const int bc   = bch / NHEADS;
    const int row0 = bc * CHUNK;
    const int tid  = threadIdx.x;
    const int lane = tid & 63;
    const int wave = tid >> 6;
    const int l15  = lane & 15;
    const int l4   = lane >> 4;

    __shared__ float sAcs[CHUNK];
    __shared__ float sdt[CHUNK];
    __shared__ bf16 xT[128 * 32];    // [p][s_local]

    sAcs[tid] = Acs[(size_t)bch * CHUNK + tid];
    sdt[tid]  = dtsp[(size_t)(row0 + tid) * NHEADS + h];
    __syncthreads();

    // frag m covers q rows qb[m] .. qb[m]+15 (interleaved across waves)
    int qb[4]; float aq[4];
#pragma unroll
    for (int m = 0; m < 4; m++) {
        qb[m] = (m * 4 + wave) * 16;
        aq[m] = sAcs[qb[m] + l15];
    }

    f32x4 acc[4][8];
#pragma unroll
    for (int m = 0; m < 4; m++)
#pragma unroll
        for (int n = 0; n < 8; n++) acc[m][n] = (f32x4){0.f, 0.f, 0.f, 0.f};

    const int sp0 = (tid & 15) * 8;
    const int ssl = 2 * (tid >> 4);

    // ---------------- diag phase ----------------
    for (int s0 = 0; s0 < CHUNK; s0 += 32) {
        __syncthreads();
        {
            const bf16* gx = xbc + (size_t)(row0 + s0 + ssl) * CONV_DIM + h * HEADDIM + sp0;
            bf16x8 v0 = *reinterpret_cast<const bf16x8*>(gx);
            bf16x8 v1 = *reinterpret_cast<const bf16x8*>(gx + CONV_DIM);
            float d0 = sdt[s0 + ssl], d1 = sdt[s0 + ssl + 1];
#pragma unroll
            for (int j = 0; j < 8; j++) {
                unsigned int px = (unsigned short)f2bs(bs2f(v0[j]) * d0) |
                                  ((unsigned int)(unsigned short)f2bs(bs2f(v1[j]) * d1) << 16);
                *reinterpret_cast<unsigned int*>(&xT[(sp0 + j) * 32 + ssl]) = px;
            }
        }
        __syncthreads();

        bf16x8 bg[8];
#pragma unroll
        for (int n = 0; n < 8; n++)
            bg[n] = *reinterpret_cast<const bf16x8*>(&xT[(n * 16 + l15) * 32 + l4 * 8]);

        f32x4 as0 = *reinterpret_cast<const f32x4*>(&sAcs[s0 + l4 * 8]);
        f32x4 as1 = *reinterpret_cast<const f32x4*>(&sAcs[s0 + l4 * 8 + 4]);

#pragma unroll
        for (int m = 0; m < 4; m++) {
            if (s0 >= qb[m] + 16) continue;          // fully masked for this frag
            int q = qb[m] + l15;
            const float* cbp = CBm + ((size_t)bc * CHUNK + q) * CHUNK + s0 + l4 * 8;
            f32x4 c0 = *reinterpret_cast<const f32x4*>(cbp);
            f32x4 c1 = *reinterpret_cast<const f32x4*>(cbp + 4);
            bf16x8 af;
#pragma unroll
            for (int j = 0; j < 8; j++) {
                int s = s0 + l4 * 8 + j;
                float cb = (j < 4) ? c0[j] : c1[j - 4];
                float a  = (j < 4) ? as0[j] : as1[j - 4];
                float w  = (s <= q) ? cb * __expf(aq[m] - a) : 0.f;
                af[j] = f2bs(w);
            }
#pragma unroll
            for (int n = 0; n < 8; n++)
                acc[m][n] = __builtin_amdgcn_mfma_f32_16x16x32_bf16(af, bg[n], acc[m][n], 0, 0, 0);
        }
    }

    // ---------------- off (prev-state) phase ----------------
    float eaq[4];
#pragma unroll
    for (int m = 0; m < 4; m++) eaq[m] = __expf(aq[m]);

    const float* prevh = prev + (size_t)bch * HEADDIM * D_STATE;
    for (int n0 = 0; n0 < D_STATE; n0 += 32) {
        bf16x8 bg[8];
#pragma unroll
        for (int n = 0; n < 8; n++) {
            const float* pr = prevh + (size_t)(n * 16 + l15) * D_STATE + n0 + l4 * 8;
            f32x4 u0 = *reinterpret_cast<const f32x4*>(pr);
            f32x4 u1 = *reinterpret_cast<const f32x4*>(pr + 4);
            bf16x8 b;
#pragma unroll
            for (int j = 0; j < 4; j++) { b[j] = f2bs(u0[j]); b[4 + j] = f2bs(u1[j]); }
            bg[n] = b;
        }
#pragma unroll
        for (int m = 0; m < 4; m++) {
            const bf16* crow = xbc + (size_t)(row0 + qb[m] + l15) * CONV_DIM
                             + D_INNER + D_STATE + n0 + l4 * 8;
            bf16x8 cv = *reinterpret_cast<const bf16x8*>(crow);
            bf16x8 af;
#pragma unroll
            for (int j = 0; j < 8; j++) af[j] = f2bs(bs2f(cv[j]) * eaq[m]);
#pragma unroll
            for (int n = 0; n < 8; n++)
                acc[m][n] = __builtin_amdgcn_mfma_f32_16x16x32_bf16(af, bg[n], acc[m][n], 0, 0, 0);
        }
    }

    // ---------------- write Y ----------------
#pragma unroll
    for (int m = 0; m < 4; m++) {
        int qrb = qb[m] + l4 * 4;
#pragma unroll
        for (int n = 0; n < 8; n++) {
            int p = n * 16 + l15;
#pragma unroll
            for (int j = 0; j < 4; j++)
                stf(&Y[(size_t)(row0 + qrb + j) * D_INNER + h * HEADDIM + p], acc[m][n][j]);
        }
    }
}

// ---------------------------------------------------------------------------
// y = (Y + D*x) * silu(z);  RMSNorm; in-place on Y (bf16)
// ---------------------------------------------------------------------------
__global__ __launch_bounds__(256) void gate_norm_kernel(
    bf16* __restrict__ Yio, const bf16* __restrict__ zx,
    const bf16* __restrict__ xbc, const float* __restrict__ Dv,
    const float* __restrict__ nw)
{
    int row = blockIdx.x;
    int t   = threadIdx.x;
    float vals[8];
    float ss = 0.f;
#pragma unroll
    for (int j = 0; j < 8; j++) {
        int d = t + 256 * j;
        float y = __bfloat162float(Yio[(size_t)row * D_INNER + d]) +
                  Dv[d >> 7] * __bfloat162float(xbc[(size_t)row * CONV_DIM + d]);
        float z = __bfloat162float(zx[(size_t)row * DIM_IN_PROJ + d]);
        y *= z * sigmoidf_(z);
        vals[j] = y;
        ss += y * y;
    }
    __shared__ float red[256];
    red[t] = ss;
    __syncthreads();
    for (int o = 128; o > 0; o >>= 1) {
        if (t < o) red[t] += red[t + o];
        __syncthreads();
    }
    float rms = rsqrtf(red[0] / (float)D_INNER + EPS);
#pragma unroll
    for (int j = 0; j < 8; j++) {
        int d = t + 256 * j;
        stf(&Yio[(size_t)row * D_INNER + d], vals[j] * rms * nw[d]);
    }
}

// ---------------------------------------------------------------------------
extern "C" void kernel_launch(void* const* d_in, const int* in_sizes, int n_in,
                              void* d_out, int out_size, void* d_ws, size_t ws_size,
                              hipStream_t stream)
{
    const float* u       = (const float*)d_in[0];
    const float* W_in    = (const float*)d_in[1];
    const float* conv_w  = (const float*)d_in[2];
    const float* conv_b  = (const float*)d_in[3];
    const float* dt_bias = (const float*)d_in[4];
    const float* A_log   = (const float*)d_in[5];
    const float* Dv      = (const float*)d_in[6];
    const float* norm_w  = (const float*)d_in[7];
    const float* W_out   = (const float*)d_in[8];
    float* out = (float*)d_out;

    char* base = (char*)d_ws;
    size_t off = 0;
    auto alloc = [&](size_t bytes) -> char* {
        char* p = base + off;
        off += (bytes + 255) & ~(size_t)255;
        return p;
    };
    bf16*  zxb    = (bf16*) alloc((size_t)ROWS * DIM_IN_PROJ * 2);                      // 71.5 MB
    bf16*  xbc    = (bf16*) alloc((size_t)ROWS * CONV_DIM * 2);                         // 37.7 MB
    float* dtraw  = (float*)alloc((size_t)ROWS * NHEADS * 4);
    float* dtsp   = (float*)alloc((size_t)ROWS * NHEADS * 4);
    float* Acs    = (float*)alloc((size_t)BATCH * NC * NHEADS * CHUNK * 4);
    float* states = (float*)alloc((size_t)BATCH * NC * NHEADS * HEADDIM * D_STATE * 4); // 33.5 MB
    float* CBm    = (float*)alloc((size_t)BATCH * NC * CHUNK * CHUNK * 4);              //  8.4 MB
    bf16*  Y      = (bf16*) alloc((size_t)ROWS * D_INNER * 2);                          // 33.5 MB
    bf16*  woutb  = (bf16*) alloc((size_t)D_MODEL * D_INNER * 2);                       //  4.2 MB
    bf16*  ub     = Y;                               // aliases: dead once y_mfma runs
    bf16*  winb   = Y + (size_t)ROWS * D_MODEL;
    if (off > ws_size) return;

    // 0. casts
    cast_bf16_kernel<<<(ROWS * D_MODEL / 4 + 255) / 256, 256, 0, stream>>>(
        (const float4*)u, (ushort4*)ub, ROWS * D_MODEL / 4);
    cast_win_kernel<<<(NPAD_WIN * D_MODEL / 4 + 255) / 256, 256, 0, stream>>>(
        (const float4*)W_in, (ushort4*)winb);
    cast_bf16_kernel<<<(D_MODEL * D_INNER / 4 + 255) / 256, 256, 0, stream>>>(
        (const float4*)W_out, (ushort4*)woutb, D_MODEL * D_INNER / 4);

    // 1. in-projection (MFMA)
    gemm_mfma_bt<bf16><<<dim3(NPAD_WIN / 128, ROWS / 128, 1), 256, 0, stream>>>(
        ub, winb, zxb, ROWS, DIM_IN_PROJ, D_MODEL, D_MODEL, D_MODEL, DIM_IN_PROJ, 0, 0, 0);

    // 1b. dt columns in fp32
    gemm_abt<float, float, float, 64, 64, 16, 4, 4>
        <<<dim3(1, ROWS / 64, 1), 256, 0, stream>>>(
        u, W_in + (size_t)(D_INNER + CONV_DIM) * D_MODEL, dtraw,
        ROWS, NHEADS, D_MODEL, D_MODEL, D_MODEL, NHEADS, 0, 0, 0);

    // 2. conv + SiLU
    conv_silu_kernel<<<(ROWS * CONV_DIM) / 256, 256, 0, stream>>>(zxb, conv_w, conv_b, xbc);

    // 3. dt softplus
    dt_softplus_kernel<<<(ROWS * NHEADS) / 256, 256, 0, stream>>>(dtraw, dt_bias, dtsp);

    // 4. cumsum of dA
    cumsum_kernel<<<BATCH * NC * NHEADS, 256, 0, stream>>>(dtsp, A_log, Acs);

    // 5. chunk states (MFMA)
    states_mfma_kernel<<<BATCH * NC * NHEADS, 256, 0, stream>>>(xbc, dtsp, Acs, states);

    // 6. inter-chunk scan (in place)
    chunkscan_kernel<<<(BATCH * NHEADS * HEADDIM * D_STATE) / 256, 256, 0, stream>>>(
        states, Acs);

    // 7. CB = C @ B^T per (b,c) (MFMA)
    gemm_mfma_bt<float><<<dim3(2, 2, BATCH * NC), 256, 0, stream>>>(
        xbc + D_INNER + D_STATE, xbc + D_INNER, CBm,
        CHUNK, CHUNK, D_STATE, CONV_DIM, CONV_DIM, CHUNK,
        (long long)CHUNK * CONV_DIM, (long long)CHUNK * CONV_DIM, (long long)CHUNK * CHUNK);

    // 8. Y (MFMA): diag + off
    y_mfma_kernel<<<BATCH * NC * NHEADS, 256, 0, stream>>>(xbc, dtsp, Acs, CBm, states, Y);

    // 9. gate + RMSNorm
    gate_norm_kernel<<<ROWS, 256, 0, stream>>>(Y, zxb, xbc, Dv, norm_w);

    // 10. out-projection (MFMA)
    gemm_mfma_bt<float><<<dim3(D_MODEL / 128, ROWS / 128, 1), 256, 0, stream>>>(
        Y, woutb, out, ROWS, D_MODEL, D_INNER, D_INNER, D_INNER, D_MODEL, 0, 0, 0);
}

// Round 5
// 423.155 us; speedup vs baseline: 7.7400x; 1.2535x over previous
//
#include <hip/hip_runtime.h>
#include <hip/hip_bf16.h>
#include <cstddef>
#include <cstdint>

#define D_MODEL     1024
#define D_INNER     2048
#define D_STATE     128
#define NHEADS      16
#define HEADDIM     128
#define D_CONV      4
#define CHUNK       256
#define CONV_DIM    2304      // D_INNER + 2*D_STATE
#define DIM_IN_PROJ 4368      // 2*D_INNER + 2*D_STATE + NHEADS
#define NPAD_WIN    4480      // 35*128, zero-padded W_in rows for MFMA tiling
#define BATCH       2
#define SEQ         4096
#define ROWS        8192      // BATCH*SEQ
#define NC          16        // SEQ/CHUNK
#define EPS         1e-5f

typedef __hip_bfloat16 bf16;
typedef __attribute__((ext_vector_type(8))) short bf16x8;
typedef __attribute__((ext_vector_type(4))) float f32x4;

__device__ __forceinline__ float sigmoidf_(float x) { return 1.f / (1.f + expf(-x)); }

__device__ __forceinline__ float ldf(const float* p) { return *p; }
__device__ __forceinline__ float ldf(const bf16* p)  { return __bfloat162float(*p); }
__device__ __forceinline__ void  stf(float* p, float v) { *p = v; }
__device__ __forceinline__ void  stf(bf16* p, float v)  { *p = __float2bfloat16(v); }

__device__ __forceinline__ short f2bs(float x) {            // float -> bf16 bits (RNE)
    bf16 h = __float2bfloat16(x);
    return __builtin_bit_cast(short, h);
}
__device__ __forceinline__ float bs2f(short s) {            // bf16 bits -> float
    unsigned int u = ((unsigned int)(unsigned short)s) << 16;
    return __builtin_bit_cast(float, u);
}

#define GLOAD_LDS16(gp, lp) \
    __builtin_amdgcn_global_load_lds((const __attribute__((address_space(1))) unsigned int*)(gp), \
        (__attribute__((address_space(3))) unsigned int*)(lp), 16, 0, 0)

// ---------------------------------------------------------------------------
// MFMA bf16 GEMM:  C[M][N] = A[M][K] * B[N][K]^T    (m97 structure)
// ---------------------------------------------------------------------------
template<typename TC>
__global__ __launch_bounds__(256) void gemm_mfma_bt(
    const bf16* __restrict__ A, const bf16* __restrict__ B, TC* __restrict__ C,
    int M, int N, int K, int lda, int ldb, int ldc,
    long long sA, long long sB, long long sC)
{
    A += (long long)blockIdx.z * sA;
    B += (long long)blockIdx.z * sB;
    C += (long long)blockIdx.z * sC;

    __shared__ bf16 As[128 * 32];
    __shared__ bf16 Bs[128 * 32];

    const int tid  = threadIdx.x;
    const int lane = tid & 63;
    const int wave = tid >> 6;
    const int wr   = wave >> 1;
    const int wc   = wave & 1;
    const int row0 = blockIdx.y * 128;
    const int col0 = blockIdx.x * 128;
    const int l15  = lane & 15;
    const int l4   = lane >> 4;

    const int srow = tid >> 2;
    const int scol = (tid & 3) * 8;

    f32x4 acc[4][4];
#pragma unroll
    for (int m = 0; m < 4; m++)
#pragma unroll
        for (int n = 0; n < 4; n++) acc[m][n] = (f32x4){0.f, 0.f, 0.f, 0.f};

    for (int k0 = 0; k0 < K; k0 += 32) {
        const bf16* gA0 = A + (size_t)(row0 + srow) * lda + k0 + scol;
        const bf16* gA1 = A + (size_t)(row0 + 64 + srow) * lda + k0 + scol;
        const bf16* gB0 = B + (size_t)(col0 + srow) * ldb + k0 + scol;
        const bf16* gB1 = B + (size_t)(col0 + 64 + srow) * ldb + k0 + scol;
        GLOAD_LDS16(gA0, &As[tid * 8]);
        GLOAD_LDS16(gA1, &As[2048 + tid * 8]);
        GLOAD_LDS16(gB0, &Bs[tid * 8]);
        GLOAD_LDS16(gB1, &Bs[2048 + tid * 8]);
        __syncthreads();

        bf16x8 af[4], bg[4];
#pragma unroll
        for (int m = 0; m < 4; m++) {
            int r = wr * 64 + m * 16 + l15;
            af[m] = *reinterpret_cast<const bf16x8*>(&As[r * 32 + l4 * 8]);
        }
#pragma unroll
        for (int n = 0; n < 4; n++) {
            int r = wc * 64 + n * 16 + l15;
            bg[n] = *reinterpret_cast<const bf16x8*>(&Bs[r * 32 + l4 * 8]);
        }
#pragma unroll
        for (int m = 0; m < 4; m++)
#pragma unroll
            for (int n = 0; n < 4; n++)
                acc[m][n] = __builtin_amdgcn_mfma_f32_16x16x32_bf16(af[m], bg[n], acc[m][n], 0, 0, 0);
        __syncthreads();
    }

#pragma unroll
    for (int m = 0; m < 4; m++) {
        int grb = row0 + wr * 64 + m * 16 + l4 * 4;
#pragma unroll
        for (int n = 0; n < 4; n++) {
            int gc = col0 + wc * 64 + n * 16 + l15;
            if (gc < N) {
#pragma unroll
                for (int j = 0; j < 4; j++) {
                    int gr = grb + j;
                    if (gr < M) stf(&C[(size_t)gr * ldc + gc], acc[m][n][j]);
                }
            }
        }
    }
}

// ---------------------------------------------------------------------------
// dt projection + softplus + bf16 cast of u, fused. One wave per row.
// dtsp[row][h] = softplus( u[row][:] . Wdt[h][:] + dt_bias[h] )
// ub[row][:]   = bf16(u[row][:])
// ---------------------------------------------------------------------------
__global__ __launch_bounds__(256) void dt_proj_kernel(
    const float* __restrict__ u, const float* __restrict__ Wdt,
    const float* __restrict__ dt_bias, float* __restrict__ dtsp,
    ushort* __restrict__ ub)
{
    const int wave = threadIdx.x >> 6;
    const int lane = threadIdx.x & 63;
    const int row  = blockIdx.x * 4 + wave;
    const float* urow = u + (size_t)row * D_MODEL;

    float4 uv[4];
#pragma unroll
    for (int w = 0; w < 4; w++)
        uv[w] = *reinterpret_cast<const float4*>(&urow[lane * 4 + w * 256]);

    // bf16 copy of u (coalesced ushort4 stores)
#pragma unroll
    for (int w = 0; w < 4; w++) {
        ushort4 o;
        o.x = (unsigned short)f2bs(uv[w].x);
        o.y = (unsigned short)f2bs(uv[w].y);
        o.z = (unsigned short)f2bs(uv[w].z);
        o.w = (unsigned short)f2bs(uv[w].w);
        *reinterpret_cast<ushort4*>(&ub[(size_t)row * D_MODEL + lane * 4 + w * 256]) = o;
    }

    float acc[NHEADS];
#pragma unroll
    for (int h = 0; h < NHEADS; h++) acc[h] = 0.f;
#pragma unroll
    for (int w = 0; w < 4; w++) {
#pragma unroll
        for (int h = 0; h < NHEADS; h++) {
            float4 wv = *reinterpret_cast<const float4*>(&Wdt[(size_t)h * D_MODEL + lane * 4 + w * 256]);
            acc[h] += uv[w].x * wv.x + uv[w].y * wv.y + uv[w].z * wv.z + uv[w].w * wv.w;
        }
    }
    // 64-lane butterfly reduce, all h
#pragma unroll
    for (int h = 0; h < NHEADS; h++)
#pragma unroll
        for (int off = 32; off > 0; off >>= 1)
            acc[h] += __shfl_xor(acc[h], off, 64);

    // static-index select (avoid runtime-indexed array -> scratch)
    float sel = 0.f;
#pragma unroll
    for (int h = 0; h < NHEADS; h++) sel = (lane == h) ? acc[h] : sel;
    if (lane < NHEADS) {
        float x = sel + dt_bias[lane];
        dtsp[(size_t)row * NHEADS + lane] = (x > 20.f) ? x : log1pf(expf(x));
    }
}

// ---------------------------------------------------------------------------
// casts (weights)
// ---------------------------------------------------------------------------
__global__ __launch_bounds__(256) void cast_bf16_kernel(
    const float4* __restrict__ src, ushort4* __restrict__ dst, int n4)
{
    int i = blockIdx.x * 256 + threadIdx.x;
    if (i >= n4) return;
    float4 v = src[i];
    ushort4 o;
    o.x = (unsigned short)f2bs(v.x);
    o.y = (unsigned short)f2bs(v.y);
    o.z = (unsigned short)f2bs(v.z);
    o.w = (unsigned short)f2bs(v.w);
    dst[i] = o;
}

__global__ __launch_bounds__(256) void cast_win_kernel(
    const float4* __restrict__ src, ushort4* __restrict__ dst)
{
    int i = blockIdx.x * 256 + threadIdx.x;
    if (i >= NPAD_WIN * D_MODEL / 4) return;
    int row = (i * 4) / D_MODEL;
    ushort4 o = {0, 0, 0, 0};
    if (row < DIM_IN_PROJ) {
        float4 v = src[i];
        o.x = (unsigned short)f2bs(v.x);
        o.y = (unsigned short)f2bs(v.y);
        o.z = (unsigned short)f2bs(v.z);
        o.w = (unsigned short)f2bs(v.w);
    }
    dst[i] = o;
}

// ---------------------------------------------------------------------------
// Depthwise causal conv (width 4) + bias + SiLU — vectorized, 8 ch/thread
// ---------------------------------------------------------------------------
__global__ __launch_bounds__(256) void conv_silu_kernel(
    const bf16* __restrict__ zx, const float* __restrict__ cw,
    const float* __restrict__ cb, bf16* __restrict__ xbc)
{
    int idx = blockIdx.x * 256 + threadIdx.x;
    if (idx >= ROWS * (CONV_DIM / 8)) return;
    int c8  = idx % (CONV_DIM / 8);
    int row = idx / (CONV_DIM / 8);
    int c0  = c8 * 8;
    int l   = row & (SEQ - 1);

    float acc[8];
    {
        float4 b0 = *reinterpret_cast<const float4*>(&cb[c0]);
        float4 b1 = *reinterpret_cast<const float4*>(&cb[c0 + 4]);
        acc[0] = b0.x; acc[1] = b0.y; acc[2] = b0.z; acc[3] = b0.w;
        acc[4] = b1.x; acc[5] = b1.y; acc[6] = b1.z; acc[7] = b1.w;
    }
    // taps per channel
    float4 t[8];
#pragma unroll
    for (int j = 0; j < 8; j++)
        t[j] = *reinterpret_cast<const float4*>(&cw[(size_t)(c0 + j) * D_CONV]);

#pragma unroll
    for (int k = 0; k < D_CONV; k++) {
        int ls = l - (D_CONV - 1) + k;
        if (ls < 0) continue;
        const bf16* zp = zx + (size_t)(row - (D_CONV - 1) + k) * DIM_IN_PROJ + D_INNER + c0;
        bf16x8 v = *reinterpret_cast<const bf16x8*>(zp);
#pragma unroll
        for (int j = 0; j < 8; j++) {
            float tap = (k == 0) ? t[j].x : (k == 1) ? t[j].y : (k == 2) ? t[j].z : t[j].w;
            acc[j] += tap * bs2f(v[j]);
        }
    }
    bf16x8 o;
#pragma unroll
    for (int j = 0; j < 8; j++) {
        float x = acc[j];
        o[j] = f2bs(x * sigmoidf_(x));
    }
    *reinterpret_cast<bf16x8*>(&xbc[(size_t)row * CONV_DIM + c0]) = o;
}

// ---------------------------------------------------------------------------
__global__ __launch_bounds__(256) void cumsum_kernel(
    const float* __restrict__ dtsp, const float* __restrict__ A_log,
    float* __restrict__ Acs)
{
    int blk = blockIdx.x;
    int h   = blk % NHEADS;
    int bc  = blk / NHEADS;
    int t   = threadIdx.x;
    int row = bc * CHUNK + t;
    float A = -expf(A_log[h]);
    __shared__ float buf[CHUNK];
    buf[t] = dtsp[(size_t)row * NHEADS + h] * A;
    __syncthreads();
    for (int off = 1; off < CHUNK; off <<= 1) {
        float v = (t >= off) ? buf[t - off] : 0.f;
        __syncthreads();
        buf[t] += v;
        __syncthreads();
    }
    Acs[(size_t)blk * CHUNK + t] = buf[t];
}

// ---------------------------------------------------------------------------
// states (MFMA): states[p][n] = sum_q xg[q,p] * B[q,n]
// ---------------------------------------------------------------------------
__global__ __launch_bounds__(256, 2) void states_mfma_kernel(
    const bf16* __restrict__ xbc, const float* __restrict__ dtsp,
    const float* __restrict__ Acs, float* __restrict__ states)
{
    const int bch  = blockIdx.x;
    const int h    = bch % NHEADS;
    const int bc   = bch / NHEADS;
    const int row0 = bc * CHUNK;
    const int tid  = threadIdx.x;
    const int lane = tid & 63;
    const int wave = tid >> 6;
    const int l15  = lane & 15;
    const int l4   = lane >> 4;

    __shared__ float g[CHUNK];
    __shared__ bf16 xT[128 * 32];
    __shared__ bf16 bT[128 * 32];

    {
        float last = Acs[(size_t)bch * CHUNK + CHUNK - 1];
        float a    = Acs[(size_t)bch * CHUNK + tid];
        g[tid] = dtsp[(size_t)(row0 + tid) * NHEADS + h] * __expf(last - a);
    }

    const int sp0 = (tid & 15) * 8;
    const int ssl = 2 * (tid >> 4);

    f32x4 acc[2][8];
#pragma unroll
    for (int m = 0; m < 2; m++)
#pragma unroll
        for (int n = 0; n < 8; n++) acc[m][n] = (f32x4){0.f, 0.f, 0.f, 0.f};

    for (int q0 = 0; q0 < CHUNK; q0 += 32) {
        __syncthreads();
        {
            const bf16* gx = xbc + (size_t)(row0 + q0 + ssl) * CONV_DIM + h * HEADDIM + sp0;
            bf16x8 v0 = *reinterpret_cast<const bf16x8*>(gx);
            bf16x8 v1 = *reinterpret_cast<const bf16x8*>(gx + CONV_DIM);
            const bf16* gb = xbc + (size_t)(row0 + q0 + ssl) * CONV_DIM + D_INNER + sp0;
            bf16x8 w0 = *reinterpret_cast<const bf16x8*>(gb);
            bf16x8 w1 = *reinterpret_cast<const bf16x8*>(gb + CONV_DIM);
            float g0 = g[q0 + ssl], g1 = g[q0 + ssl + 1];
#pragma unroll
            for (int j = 0; j < 8; j++) {
                unsigned int px = (unsigned short)f2bs(bs2f(v0[j]) * g0) |
                                  ((unsigned int)(unsigned short)f2bs(bs2f(v1[j]) * g1) << 16);
                *reinterpret_cast<unsigned int*>(&xT[(sp0 + j) * 32 + ssl]) = px;
                unsigned int pb = (unsigned short)w0[j] |
                                  ((unsigned int)(unsigned short)w1[j] << 16);
                *reinterpret_cast<unsigned int*>(&bT[(sp0 + j) * 32 + ssl]) = pb;
            }
        }
        __syncthreads();

        bf16x8 af[2], bg[8];
#pragma unroll
        for (int m = 0; m < 2; m++) {
            int p = wave * 32 + m * 16 + l15;
            af[m] = *reinterpret_cast<const bf16x8*>(&xT[p * 32 + l4 * 8]);
        }
#pragma unroll
        for (int n = 0; n < 8; n++) {
            int nn = n * 16 + l15;
            bg[n] = *reinterpret_cast<const bf16x8*>(&bT[nn * 32 + l4 * 8]);
        }
#pragma unroll
        for (int m = 0; m < 2; m++)
#pragma unroll
            for (int n = 0; n < 8; n++)
                acc[m][n] = __builtin_amdgcn_mfma_f32_16x16x32_bf16(af[m], bg[n], acc[m][n], 0, 0, 0);
    }

    float* sp = states + (size_t)bch * HEADDIM * D_STATE;
#pragma unroll
    for (int m = 0; m < 2; m++) {
        int pb = wave * 32 + m * 16 + l4 * 4;
#pragma unroll
        for (int n = 0; n < 8; n++) {
            int nn = n * 16 + l15;
#pragma unroll
            for (int j = 0; j < 4; j++)
                sp[(size_t)(pb + j) * D_STATE + nn] = acc[m][n][j];
        }
    }
}

// ---------------------------------------------------------------------------
// Sequential inter-chunk scan, IN PLACE on states
// ---------------------------------------------------------------------------
__global__ __launch_bounds__(256) void chunkscan_kernel(
    float* __restrict__ states, const float* __restrict__ Acs)
{
    int idx = blockIdx.x * 256 + threadIdx.x;
    int pn  = idx % (HEADDIM * D_STATE);
    int bh  = idx / (HEADDIM * D_STATE);
    int h   = bh % NHEADS;
    int b   = bh / NHEADS;
    float carry = 0.f;
    for (int c = 0; c < NC; c++) {
        int bch = (b * NC + c) * NHEADS + h;
        size_t off = (size_t)bch * HEADDIM * D_STATE + pn;
        float s   = states[off];
        states[off] = carry;
        float dec = expf(Acs[(size_t)bch * CHUNK + CHUNK - 1]);
        carry = carry * dec + s;
    }
}

// ---------------------------------------------------------------------------
// Y (MFMA): diag (causal, CB*L) + off (prev-state) per (b,c,h)
// ---------------------------------------------------------------------------
__global__ __launch_bounds__(256, 2) void y_mfma_kernel(
    const bf16* __restrict__ xbc, const float* __restrict__ dtsp,
    const float* __restrict__ Acs, const float* __restrict__ CBm,
    const float* __restrict__ prev, bf16* __restrict__ Y)
{
    const int bch  = blockIdx.x;
    const int h    = bch % NHEADS;
    const int bc   = bch / NHEADS;
    const int row0 = bc * CHUNK;
    const int tid  = threadIdx.x;
    const int lane = tid & 63;
    const int wave = tid >> 6;
    const int l15  = lane & 15;
    const int l4   = lane >> 4;

    __shared__ float sAcs[CHUNK];
    __shared__ float sdt[CHUNK];
    __shared__ bf16 xT[128 * 32];

    sAcs[tid] = Acs[(size_t)bch * CHUNK + tid];
    sdt[tid]  = dtsp[(size_t)(row0 + tid) * NHEADS + h];
    __syncthreads();

    int qb[4]; float aq[4];
#pragma unroll
    for (int m = 0; m < 4; m++) {
        qb[m] = (m * 4 + wave) * 16;
        aq[m] = sAcs[qb[m] + l15];
    }

    f32x4 acc[4][8];
#pragma unroll
    for (int m = 0; m < 4; m++)
#pragma unroll
        for (int n = 0; n < 8; n++) acc[m][n] = (f32x4){0.f, 0.f, 0.f, 0.f};

    const int sp0 = (tid & 15) * 8;
    const int ssl = 2 * (tid >> 4);

    // ---------------- diag phase ----------------
    for (int s0 = 0; s0 < CHUNK; s0 += 32) {
        __syncthreads();
        {
            const bf16* gx = xbc + (size_t)(row0 + s0 + ssl) * CONV_DIM + h * HEADDIM + sp0;
            bf16x8 v0 = *reinterpret_cast<const bf16x8*>(gx);
            bf16x8 v1 = *reinterpret_cast<const bf16x8*>(gx + CONV_DIM);
            float d0 = sdt[s0 + ssl], d1 = sdt[s0 + ssl + 1];
#pragma unroll
            for (int j = 0; j < 8; j++) {
                unsigned int px = (unsigned short)f2bs(bs2f(v0[j]) * d0) |
                                  ((unsigned int)(unsigned short)f2bs(bs2f(v1[j]) * d1) << 16);
                *reinterpret_cast<unsigned int*>(&xT[(sp0 + j) * 32 + ssl]) = px;
            }
        }
        __syncthreads();

        bf16x8 bg[8];
#pragma unroll
        for (int n = 0; n < 8; n++)
            bg[n] = *reinterpret_cast<const bf16x8*>(&xT[(n * 16 + l15) * 32 + l4 * 8]);

        f32x4 as0 = *reinterpret_cast<const f32x4*>(&sAcs[s0 + l4 * 8]);
        f32x4 as1 = *reinterpret_cast<const f32x4*>(&sAcs[s0 + l4 * 8 + 4]);

#pragma unroll
        for (int m = 0; m < 4; m++) {
            if (s0 >= qb[m] + 16) continue;
            int q = qb[m] + l15;
            const float* cbp = CBm + ((size_t)bc * CHUNK + q) * CHUNK + s0 + l4 * 8;
            f32x4 c0 = *reinterpret_cast<const f32x4*>(cbp);
            f32x4 c1 = *reinterpret_cast<const f32x4*>(cbp + 4);
            bf16x8 af;
#pragma unroll
            for (int j = 0; j < 8; j++) {
                int s = s0 + l4 * 8 + j;
                float cb = (j < 4) ? c0[j] : c1[j - 4];
                float a  = (j < 4) ? as0[j] : as1[j - 4];
                float w  = (s <= q) ? cb * __expf(aq[m] - a) : 0.f;
                af[j] = f2bs(w);
            }
#pragma unroll
            for (int n = 0; n < 8; n++)
                acc[m][n] = __builtin_amdgcn_mfma_f32_16x16x32_bf16(af, bg[n], acc[m][n], 0, 0, 0);
        }
    }

    // ---------------- off (prev-state) phase ----------------
    float eaq[4];
#pragma unroll
    for (int m = 0; m < 4; m++) eaq[m] = __expf(aq[m]);

    const float* prevh = prev + (size_t)bch * HEADDIM * D_STATE;
    for (int n0 = 0; n0 < D_STATE; n0 += 32) {
        bf16x8 bg[8];
#pragma unroll
        for (int n = 0; n < 8; n++) {
            const float* pr = prevh + (size_t)(n * 16 + l15) * D_STATE + n0 + l4 * 8;
            f32x4 u0 = *reinterpret_cast<const f32x4*>(pr);
            f32x4 u1 = *reinterpret_cast<const f32x4*>(pr + 4);
            bf16x8 b;
#pragma unroll
            for (int j = 0; j < 4; j++) { b[j] = f2bs(u0[j]); b[4 + j] = f2bs(u1[j]); }
            bg[n] = b;
        }
#pragma unroll
        for (int m = 0; m < 4; m++) {
            const bf16* crow = xbc + (size_t)(row0 + qb[m] + l15) * CONV_DIM
                             + D_INNER + D_STATE + n0 + l4 * 8;
            bf16x8 cv = *reinterpret_cast<const bf16x8*>(crow);
            bf16x8 af;
#pragma unroll
            for (int j = 0; j < 8; j++) af[j] = f2bs(bs2f(cv[j]) * eaq[m]);
#pragma unroll
            for (int n = 0; n < 8; n++)
                acc[m][n] = __builtin_amdgcn_mfma_f32_16x16x32_bf16(af, bg[n], acc[m][n], 0, 0, 0);
        }
    }

    // ---------------- write Y ----------------
#pragma unroll
    for (int m = 0; m < 4; m++) {
        int qrb = qb[m] + l4 * 4;
#pragma unroll
        for (int n = 0; n < 8; n++) {
            int p = n * 16 + l15;
#pragma unroll
            for (int j = 0; j < 4; j++)
                stf(&Y[(size_t)(row0 + qrb + j) * D_INNER + h * HEADDIM + p], acc[m][n][j]);
        }
    }
}

// ---------------------------------------------------------------------------
// y = (Y + D*x) * silu(z);  RMSNorm; in-place on Y (bf16) — vectorized
// ---------------------------------------------------------------------------
__global__ __launch_bounds__(256) void gate_norm_kernel(
    bf16* __restrict__ Yio, const bf16* __restrict__ zx,
    const bf16* __restrict__ xbc, const float* __restrict__ Dv,
    const float* __restrict__ nw)
{
    int row = blockIdx.x;
    int t   = threadIdx.x;
    int d0  = t * 8;

    bf16x8 yv = *reinterpret_cast<const bf16x8*>(&Yio[(size_t)row * D_INNER + d0]);
    bf16x8 xv = *reinterpret_cast<const bf16x8*>(&xbc[(size_t)row * CONV_DIM + d0]);
    bf16x8 zv = *reinterpret_cast<const bf16x8*>(&zx[(size_t)row * DIM_IN_PROJ + d0]);
    float Dh = Dv[d0 >> 7];

    float vals[8];
    float ss = 0.f;
#pragma unroll
    for (int j = 0; j < 8; j++) {
        float y = bs2f(yv[j]) + Dh * bs2f(xv[j]);
        float z = bs2f(zv[j]);
        y *= z * sigmoidf_(z);
        vals[j] = y;
        ss += y * y;
    }
    __shared__ float red[256];
    red[t] = ss;
    __syncthreads();
    for (int o = 128; o > 0; o >>= 1) {
        if (t < o) red[t] += red[t + o];
        __syncthreads();
    }
    float rms = rsqrtf(red[0] / (float)D_INNER + EPS);

    float4 w0 = *reinterpret_cast<const float4*>(&nw[d0]);
    float4 w1 = *reinterpret_cast<const float4*>(&nw[d0 + 4]);
    bf16x8 o;
    o[0] = f2bs(vals[0] * rms * w0.x);
    o[1] = f2bs(vals[1] * rms * w0.y);
    o[2] = f2bs(vals[2] * rms * w0.z);
    o[3] = f2bs(vals[3] * rms * w0.w);
    o[4] = f2bs(vals[4] * rms * w1.x);
    o[5] = f2bs(vals[5] * rms * w1.y);
    o[6] = f2bs(vals[6] * rms * w1.z);
    o[7] = f2bs(vals[7] * rms * w1.w);
    *reinterpret_cast<bf16x8*>(&Yio[(size_t)row * D_INNER + d0]) = o;
}

// ---------------------------------------------------------------------------
extern "C" void kernel_launch(void* const* d_in, const int* in_sizes, int n_in,
                              void* d_out, int out_size, void* d_ws, size_t ws_size,
                              hipStream_t stream)
{
    const float* u       = (const float*)d_in[0];
    const float* W_in    = (const float*)d_in[1];
    const float* conv_w  = (const float*)d_in[2];
    const float* conv_b  = (const float*)d_in[3];
    const float* dt_bias = (const float*)d_in[4];
    const float* A_log   = (const float*)d_in[5];
    const float* Dv      = (const float*)d_in[6];
    const float* norm_w  = (const float*)d_in[7];
    const float* W_out   = (const float*)d_in[8];
    float* out = (float*)d_out;

    char* base = (char*)d_ws;
    size_t off = 0;
    auto alloc = [&](size_t bytes) -> char* {
        char* p = base + off;
        off += (bytes + 255) & ~(size_t)255;
        return p;
    };
    bf16*  zxb    = (bf16*) alloc((size_t)ROWS * DIM_IN_PROJ * 2);                      // 71.5 MB
    bf16*  xbc    = (bf16*) alloc((size_t)ROWS * CONV_DIM * 2);                         // 37.7 MB
    float* dtsp   = (float*)alloc((size_t)ROWS * NHEADS * 4);
    float* Acs    = (float*)alloc((size_t)BATCH * NC * NHEADS * CHUNK * 4);
    float* states = (float*)alloc((size_t)BATCH * NC * NHEADS * HEADDIM * D_STATE * 4); // 33.5 MB
    float* CBm    = (float*)alloc((size_t)BATCH * NC * CHUNK * CHUNK * 4);              //  8.4 MB
    bf16*  Y      = (bf16*) alloc((size_t)ROWS * D_INNER * 2);                          // 33.5 MB
    bf16*  woutb  = (bf16*) alloc((size_t)D_MODEL * D_INNER * 2);                       //  4.2 MB
    bf16*  ub     = Y;                               // aliases: dead once y_mfma runs
    bf16*  winb   = Y + (size_t)ROWS * D_MODEL;
    if (off > ws_size) return;

    // 0. dt projection (fp32) + softplus + u->bf16 cast, fused
    dt_proj_kernel<<<ROWS / 4, 256, 0, stream>>>(
        u, W_in + (size_t)(D_INNER + CONV_DIM) * D_MODEL, dt_bias, dtsp, (ushort*)ub);

    // 0b. weight casts
    cast_win_kernel<<<(NPAD_WIN * D_MODEL / 4 + 255) / 256, 256, 0, stream>>>(
        (const float4*)W_in, (ushort4*)winb);
    cast_bf16_kernel<<<(D_MODEL * D_INNER / 4 + 255) / 256, 256, 0, stream>>>(
        (const float4*)W_out, (ushort4*)woutb, D_MODEL * D_INNER / 4);

    // 1. in-projection (MFMA)
    gemm_mfma_bt<bf16><<<dim3(NPAD_WIN / 128, ROWS / 128, 1), 256, 0, stream>>>(
        ub, winb, zxb, ROWS, DIM_IN_PROJ, D_MODEL, D_MODEL, D_MODEL, DIM_IN_PROJ, 0, 0, 0);

    // 2. conv + SiLU (vectorized)
    conv_silu_kernel<<<(ROWS * (CONV_DIM / 8)) / 256, 256, 0, stream>>>(
        zxb, conv_w, conv_b, xbc);

    // 4. cumsum of dA
    cumsum_kernel<<<BATCH * NC * NHEADS, 256, 0, stream>>>(dtsp, A_log, Acs);

    // 5. chunk states (MFMA)
    states_mfma_kernel<<<BATCH * NC * NHEADS, 256, 0, stream>>>(xbc, dtsp, Acs, states);

    // 6. inter-chunk scan (in place)
    chunkscan_kernel<<<(BATCH * NHEADS * HEADDIM * D_STATE) / 256, 256, 0, stream>>>(
        states, Acs);

    // 7. CB = C @ B^T per (b,c) (MFMA)
    gemm_mfma_bt<float><<<dim3(2, 2, BATCH * NC), 256, 0, stream>>>(
        xbc + D_INNER + D_STATE, xbc + D_INNER, CBm,
        CHUNK, CHUNK, D_STATE, CONV_DIM, CONV_DIM, CHUNK,
        (long long)CHUNK * CONV_DIM, (long long)CHUNK * CONV_DIM, (long long)CHUNK * CHUNK);

    // 8. Y (MFMA): diag + off
    y_mfma_kernel<<<BATCH * NC * NHEADS, 256, 0, stream>>>(xbc, dtsp, Acs, CBm, states, Y);

    // 9. gate + RMSNorm
    gate_norm_kernel<<<ROWS, 256, 0, stream>>>(Y, zxb, xbc, Dv, norm_w);

    // 10. out-projection (MFMA)
    gemm_mfma_bt<float><<<dim3(D_MODEL / 128, ROWS / 128, 1), 256, 0, stream>>>(
        Y, woutb, out, ROWS, D_MODEL, D_INNER, D_INNER, D_INNER, D_MODEL, 0, 0, 0);
}